// Round 2
// baseline (13008.615 us; speedup 1.0000x reference)
//
#include <hip/hip_runtime.h>
#include <hip/hip_bf16.h>

// nGPT-style transformer layer, MI355X. Round 1: fp32 correctness baseline,
// attention K-offset bug fixed (was dotting Q_query with Q_key).
// B=4 T=2048 dm=1024 H=16 di=64.
//
// Workspace arena (peak 224 MiB, overlap-reuse):
//   [0,        33.5M)  x1           fp32 [8192][1024]         (live to end)
//   [33.5M,   134.2M)  QKV          fp32 [16][8192][192]      (dead after attn)
//   [134.2M,  167.8M)  attn_out     fp32 [8192][1024]         (dead after W_O gemm)
//   [167.8M,  201.3M)  t            fp32 [8192][1024]         (dead after lerp1)
//   [33.5M,   167.8M)  uv           bf16 [8192][8192]         (reuses QKV+attn)
//   [167.8M,  234.9M)  res          bf16 [8192][4096]         (reuses t)
//   [33.5M,    67.1M)  t2           fp32 [8192][1024]         (reuses uv)

#define B_   4
#define T_   2048
#define DM   1024
#define H_   16
#define DI   64
#define NROW (B_ * T_)   // 8192

using bf16 = __hip_bfloat16;

__device__ __forceinline__ float ldf(const float* p) { return *p; }
__device__ __forceinline__ float ldf(const bf16* p)  { return __bfloat162float(*p); }
__device__ __forceinline__ void  stf(float* p, float v) { *p = v; }
__device__ __forceinline__ void  stf(bf16* p, float v)  { *p = __float2bfloat16(v); }

__device__ __forceinline__ float wave_sum(float v) {
#pragma unroll
    for (int off = 32; off; off >>= 1) v += __shfl_xor(v, off, 64);
    return v;
}

// block-wide sum for 256-thread blocks (4 waves)
__device__ __forceinline__ float block_sum(float v) {
    __shared__ float sm[4];
    int lane = threadIdx.x & 63, w = threadIdx.x >> 6;
    v = wave_sum(v);
    __syncthreads();                 // protect sm reuse across calls
    if (lane == 0) sm[w] = v;
    __syncthreads();
    return sm[0] + sm[1] + sm[2] + sm[3];
}

// ---------------------------------------------------------------------------
// C = A * B^T  (both A,B row-major with K contiguous). 64x64 tile, BK=16,
// 256 threads, 4x4 microtile per thread. Batched via blockIdx.z.
// All dims assumed divisible by tile (true for every call below).
// ---------------------------------------------------------------------------
template <typename TA, typename TB, typename TC>
__global__ __launch_bounds__(256)
void gemm_nt(const TA* __restrict__ A, const TB* __restrict__ Bm, TC* __restrict__ C,
             int M, int N, int K, long sA, long sB, long sC)
{
    A  += (long)blockIdx.z * sA;
    Bm += (long)blockIdx.z * sB;
    C  += (long)blockIdx.z * sC;

    __shared__ float As[16][64];
    __shared__ float Bs[16][64];

    const int tid = threadIdx.x;
    const int tx = tid & 15, ty = tid >> 4;
    const int m0 = blockIdx.y * 64, n0 = blockIdx.x * 64;
    const int r  = tid >> 2;            // 0..63
    const int kk = (tid & 3) << 2;      // 0,4,8,12

    float acc[4][4] = {};

    for (int k0 = 0; k0 < K; k0 += 16) {
        const TA* pa = A  + (long)(m0 + r) * K + (k0 + kk);
        const TB* pb = Bm + (long)(n0 + r) * K + (k0 + kk);
        float a0 = ldf(pa + 0), a1 = ldf(pa + 1), a2 = ldf(pa + 2), a3 = ldf(pa + 3);
        float b0 = ldf(pb + 0), b1 = ldf(pb + 1), b2 = ldf(pb + 2), b3 = ldf(pb + 3);
        __syncthreads();                // previous iter done reading LDS
        As[kk + 0][r] = a0; As[kk + 1][r] = a1; As[kk + 2][r] = a2; As[kk + 3][r] = a3;
        Bs[kk + 0][r] = b0; Bs[kk + 1][r] = b1; Bs[kk + 2][r] = b2; Bs[kk + 3][r] = b3;
        __syncthreads();
#pragma unroll
        for (int k = 0; k < 16; k++) {
            float4 a4 = *(const float4*)&As[k][ty << 2];
            float4 b4 = *(const float4*)&Bs[k][tx << 2];
            float av[4] = {a4.x, a4.y, a4.z, a4.w};
            float bv[4] = {b4.x, b4.y, b4.z, b4.w};
#pragma unroll
            for (int i = 0; i < 4; i++)
#pragma unroll
                for (int j = 0; j < 4; j++)
                    acc[i][j] = fmaf(av[i], bv[j], acc[i][j]);
        }
    }

#pragma unroll
    for (int i = 0; i < 4; i++)
#pragma unroll
        for (int j = 0; j < 4; j++)
            stf(&C[(long)(m0 + (ty << 2) + i) * N + n0 + (tx << 2) + j], acc[i][j]);
}

// ---------------------------------------------------------------------------
// In-place RoPE + per-row L2 norm + sqk*sqrt(dm) scaling on Q,K halves of QKV.
// One wave per (h, b*T+t). lane = d in [0,64).
// ---------------------------------------------------------------------------
__global__ __launch_bounds__(256)
void rope_norm_qk(float* __restrict__ QKV, const float* __restrict__ sqk)
{
    int gw   = (blockIdx.x * 256 + threadIdx.x) >> 6;   // 0 .. H*NROW-1
    int lane = threadIdx.x & 63;
    int h = gw / NROW, row = gw % NROW, t = row % T_;

    float* base = QKV + ((long)h * NROW + row) * 192;
    float q = base[lane], k = base[64 + lane];

    int   j   = lane & 31;
    // inv_freq = 10000^(-j/32) = exp(-j * ln(10000)/32)
    float inv = expf(-(float)j * (9.210340371976184f / 32.f));
    float ang = (float)t * inv;
    float s = sinf(ang), c = cosf(ang);

    float qp = __shfl_xor(q, 32, 64);
    float kp = __shfl_xor(k, 32, 64);
    float sgn = (lane < 32) ? -1.f : 1.f;
    float qr = q * c + sgn * qp * s;
    float kr = k * c + sgn * kp * s;

    float qs = wave_sum(qr * qr);
    float ks = wave_sum(kr * kr);
    float se = sqk[h * 64 + lane] * 32.f;   // sqk * sqrt(dm)

    base[lane]      = qr * rsqrtf(qs) * se;
    base[64 + lane] = kr * rsqrtf(ks) * se;
}

// ---------------------------------------------------------------------------
// Causal attention, online softmax. One wave per (b,h,tq); lane = d.
// scores = (Q.K) * sqrt(dm).  Output layout [b*T+t][h*64+d].
// ---------------------------------------------------------------------------
__global__ __launch_bounds__(256)
void attn_fwd(const float* __restrict__ QKV, float* __restrict__ O)
{
    int gw   = (blockIdx.x * 256 + threadIdx.x) >> 6;   // 0 .. B*H*T-1
    int lane = threadIdx.x & 63;
    int h  = gw / (B_ * T_);
    int bt = gw % (B_ * T_);
    int b  = bt / T_, tq = bt % T_;

    const float* qrow = QKV + ((long)h * NROW + bt) * 192;
    float q = qrow[lane];
    const float* kv0 = QKV + ((long)h * NROW + (long)b * T_) * 192;

    float m = -3.0e38f, l = 0.f, o = 0.f;
    for (int k = 0; k <= tq; k++) {
        const float* krow = kv0 + (long)k * 192;
        float p = q * krow[64 + lane];          // K is at offset 64 (FIX)
        p = wave_sum(p) * 32.f;                 // * sqrt(dm)
        float mn   = fmaxf(m, p);
        float corr = __expf(m - mn);
        float e    = __expf(p - mn);
        l = l * corr + e;
        o = o * corr + e * krow[128 + lane];    // V
        m = mn;
    }
    O[(long)bt * DM + h * DI + lane] = o / l;
}

// ---------------------------------------------------------------------------
// Out = justnorm(A + lr*(Bn - A)),  A=justnorm(X row), Bn=justnorm(T row),
// lr = |alpha * ascale|.  One 256-thread block per row of 1024.
// ---------------------------------------------------------------------------
__global__ __launch_bounds__(256)
void lerp_norm(const float* __restrict__ X, const float* __restrict__ Tt,
               const float* __restrict__ alpha, float ascale, float* __restrict__ Out)
{
    long row = blockIdx.x;
    const float* xr = X  + row * DM;
    const float* tr = Tt + row * DM;
    int tid = threadIdx.x;

    float xs[4], ts[4], sx = 0.f, st = 0.f;
#pragma unroll
    for (int i = 0; i < 4; i++) {
        int d = tid + 256 * i;
        xs[i] = xr[d]; ts[i] = tr[d];
        sx += xs[i] * xs[i]; st += ts[i] * ts[i];
    }
    sx = block_sum(sx);
    st = block_sum(st);
    float ix = rsqrtf(sx), it = rsqrtf(st);

    float ys[4], sy = 0.f;
#pragma unroll
    for (int i = 0; i < 4; i++) {
        int d = tid + 256 * i;
        float a  = xs[i] * ix;
        float bn = ts[i] * it;
        float lr = fabsf(alpha[d] * ascale);
        ys[i] = a + lr * (bn - a);
        sy += ys[i] * ys[i];
    }
    sy = block_sum(sy);
    float iy = rsqrtf(sy);
#pragma unroll
    for (int i = 0; i < 4; i++) {
        int d = tid + 256 * i;
        Out[row * DM + d] = ys[i] * iy;
    }
}

// ---------------------------------------------------------------------------
// tn = justnorm(suv*sqrt(dm) * uv_row[8192]); u,v = split(tn); res = u*silu(v)
// One block per row.
// ---------------------------------------------------------------------------
__global__ __launch_bounds__(256)
void mlp_act(const bf16* __restrict__ UV, const float* __restrict__ suv,
             bf16* __restrict__ R)
{
    long row = blockIdx.x;
    const bf16* ur = UV + row * 8192;
    int tid = threadIdx.x;

    float ss = 0.f;
#pragma unroll
    for (int i = 0; i < 32; i++) {
        int j = tid + 256 * i;
        float v = __bfloat162float(ur[j]) * suv[j] * 32.f;
        ss += v * v;
    }
    ss = block_sum(ss);
    float inv = rsqrtf(ss);

#pragma unroll
    for (int i = 0; i < 16; i++) {
        int j = tid + 256 * i;
        float u = __bfloat162float(ur[j])        * suv[j]        * 32.f * inv;
        float v = __bfloat162float(ur[4096 + j]) * suv[4096 + j] * 32.f * inv;
        float sil = v / (1.f + __expf(-v));
        R[row * 4096 + j] = __float2bfloat16(u * sil);
    }
}

// ---------------------------------------------------------------------------
extern "C" void kernel_launch(void* const* d_in, const int* in_sizes, int n_in,
                              void* d_out, int out_size, void* d_ws, size_t ws_size,
                              hipStream_t stream)
{
    const float* x          = (const float*)d_in[0];
    const float* qkv_w      = (const float*)d_in[1];
    const float* sqk        = (const float*)d_in[2];
    const float* W_O        = (const float*)d_in[3];
    const float* Wu         = (const float*)d_in[4];
    const float* Wv         = (const float*)d_in[5];
    const float* attn_alpha = (const float*)d_in[6];
    const float* mlp_alpha  = (const float*)d_in[7];
    const float* suv        = (const float*)d_in[8];
    float* out = (float*)d_out;

    char* ws = (char*)d_ws;
    float* x1    = (float*)(ws + 0);
    float* QKV   = (float*)(ws + 33554432);
    float* attno = (float*)(ws + 134217728);
    float* tbuf  = (float*)(ws + 167772160);
    bf16*  uv    = (bf16*) (ws + 33554432);
    bf16*  res   = (bf16*) (ws + 167772160);
    float* t2    = (float*)(ws + 33554432);
    // requires ws_size >= 234881024 bytes

    // 1) per-head QKV projection: [8192x1024] x [192x1024]^T, batched over H
    gemm_nt<float, float, float><<<dim3(3, 128, 16), 256, 0, stream>>>(
        x, qkv_w, QKV, NROW, 192, DM, 0L, 192L * 1024, (long)NROW * 192);

    // 2) RoPE + justnorm + sqk scaling on Q,K (in place)
    rope_norm_qk<<<(H_ * NROW) / 4, 256, 0, stream>>>(QKV, sqk);

    // 3) causal SDPA, scale sqrt(dm)
    attn_fwd<<<(B_ * H_ * T_) / 4, 256, 0, stream>>>(QKV, attno);

    // 4) W_O projection
    gemm_nt<float, float, float><<<dim3(16, 128, 1), 256, 0, stream>>>(
        attno, W_O, tbuf, NROW, DM, DM, 0L, 0L, 0L);

    // 5) attention residual lerp-norm -> x1
    lerp_norm<<<NROW, 256, 0, stream>>>(x, tbuf, attn_alpha, 1.6f, x1);

    // 6) uv = x1 @ Wu^T  -> bf16
    gemm_nt<float, float, bf16><<<dim3(128, 128, 1), 256, 0, stream>>>(
        x1, Wu, uv, NROW, 8 * DM, DM, 0L, 0L, 0L);

    // 7) row-normalize(8192) + SwiGLU activation -> res bf16
    mlp_act<<<NROW, 256, 0, stream>>>(uv, suv, res);

    // 8) t2 = res @ Wv^T
    gemm_nt<bf16, float, float><<<dim3(16, 128, 1), 256, 0, stream>>>(
        res, Wv, t2, NROW, DM, 4 * DM, 0L, 0L, 0L);

    // 9) MLP residual lerp-norm -> out
    lerp_norm<<<NROW, 256, 0, stream>>>(x1, t2, mlp_alpha, 0.05f, out);
}

// Round 3
// 4079.417 us; speedup vs baseline: 3.1888x; 3.1888x over previous
//
#include <hip/hip_runtime.h>
#include <hip/hip_bf16.h>

// nGPT-style transformer layer, MI355X. Round 2: MFMA flash attention (bf16).
// B=4 T=2048 dm=1024 H=16 di=64.
//
// Workspace arena (peak 224 MiB, overlap-reuse):
//   [0,        33.5M)  x1     fp32 [8192][1024]      (live to end)
//   [33.5M,   134.2M)  QKV    fp32 [16][8192][192]   (dead after rope)
//   [134.2M,  167.8M)  attno  fp32 [8192][1024]      (dead after W_O gemm)
//   [167.8M,  184.5M)  Qb     bf16 [16][8192][64]    (dead after attn)
//   [184.5M,  201.3M)  Kb     bf16 [16][8192][64]    (dead after attn)
//   [201.3M,  218.1M)  Vt     bf16 [16][4][64][2048] (dead after attn)
//   [167.8M,  201.3M)  tbuf   fp32 [8192][1024]      (reuses Qb/Kb, after attn)
//   [33.5M,   167.8M)  uv     bf16 [8192][8192]      (reuses QKV+attno)
//   [167.8M,  234.9M)  res    bf16 [8192][4096]      (reuses tbuf/Vt)
//   [33.5M,    67.1M)  t2     fp32 [8192][1024]      (reuses uv)

#define B_   4
#define T_   2048
#define DM   1024
#define H_   16
#define DI   64
#define NROW (B_ * T_)   // 8192

using bf16 = __hip_bfloat16;
typedef __attribute__((ext_vector_type(8))) short bfrag;   // 8 bf16 (4 VGPR)
typedef __attribute__((ext_vector_type(4))) float f4;

__device__ __forceinline__ float ldf(const float* p) { return *p; }
__device__ __forceinline__ float ldf(const bf16* p)  { return __bfloat162float(*p); }
__device__ __forceinline__ void  stf(float* p, float v) { *p = v; }
__device__ __forceinline__ void  stf(bf16* p, float v)  { *p = __float2bfloat16(v); }

__device__ __forceinline__ unsigned short bfbits(float a) {
    bf16 h = __float2bfloat16(a);
    return __builtin_bit_cast(unsigned short, h);
}
__device__ __forceinline__ unsigned pk2(float a, float b) {
    return (unsigned)bfbits(a) | ((unsigned)bfbits(b) << 16);
}

__device__ __forceinline__ float wave_sum(float v) {
#pragma unroll
    for (int off = 32; off; off >>= 1) v += __shfl_xor(v, off, 64);
    return v;
}

__device__ __forceinline__ float block_sum(float v) {
    __shared__ float sm[4];
    int lane = threadIdx.x & 63, w = threadIdx.x >> 6;
    v = wave_sum(v);
    __syncthreads();
    if (lane == 0) sm[w] = v;
    __syncthreads();
    return sm[0] + sm[1] + sm[2] + sm[3];
}

// ---------------------------------------------------------------------------
// C = A * B^T  (both row-major, K contiguous). 64x64 tile, BK=16, 256 thr.
// ---------------------------------------------------------------------------
template <typename TA, typename TB, typename TC>
__global__ __launch_bounds__(256)
void gemm_nt(const TA* __restrict__ A, const TB* __restrict__ Bm, TC* __restrict__ C,
             int M, int N, int K, long sA, long sB, long sC)
{
    A  += (long)blockIdx.z * sA;
    Bm += (long)blockIdx.z * sB;
    C  += (long)blockIdx.z * sC;

    __shared__ float As[16][64];
    __shared__ float Bs[16][64];

    const int tid = threadIdx.x;
    const int tx = tid & 15, ty = tid >> 4;
    const int m0 = blockIdx.y * 64, n0 = blockIdx.x * 64;
    const int r  = tid >> 2;
    const int kk = (tid & 3) << 2;

    float acc[4][4] = {};

    for (int k0 = 0; k0 < K; k0 += 16) {
        const TA* pa = A  + (long)(m0 + r) * K + (k0 + kk);
        const TB* pb = Bm + (long)(n0 + r) * K + (k0 + kk);
        float a0 = ldf(pa + 0), a1 = ldf(pa + 1), a2 = ldf(pa + 2), a3 = ldf(pa + 3);
        float b0 = ldf(pb + 0), b1 = ldf(pb + 1), b2 = ldf(pb + 2), b3 = ldf(pb + 3);
        __syncthreads();
        As[kk + 0][r] = a0; As[kk + 1][r] = a1; As[kk + 2][r] = a2; As[kk + 3][r] = a3;
        Bs[kk + 0][r] = b0; Bs[kk + 1][r] = b1; Bs[kk + 2][r] = b2; Bs[kk + 3][r] = b3;
        __syncthreads();
#pragma unroll
        for (int k = 0; k < 16; k++) {
            float4 a4 = *(const float4*)&As[k][ty << 2];
            float4 b4 = *(const float4*)&Bs[k][tx << 2];
            float av[4] = {a4.x, a4.y, a4.z, a4.w};
            float bv[4] = {b4.x, b4.y, b4.z, b4.w};
#pragma unroll
            for (int i = 0; i < 4; i++)
#pragma unroll
                for (int j = 0; j < 4; j++)
                    acc[i][j] = fmaf(av[i], bv[j], acc[i][j]);
        }
    }

#pragma unroll
    for (int i = 0; i < 4; i++)
#pragma unroll
        for (int j = 0; j < 4; j++)
            stf(&C[(long)(m0 + (ty << 2) + i) * N + n0 + (tx << 2) + j], acc[i][j]);
}

// ---------------------------------------------------------------------------
// RoPE + per-row L2 norm + sqk*sqrt(dm) scaling; emit bf16 Q (x32 sdpa scale
// folded in), bf16 K, and V transposed Vt[h][b][d][T]. One wave per (h,row).
// ---------------------------------------------------------------------------
__global__ __launch_bounds__(256)
void rope_norm_qk(const float* __restrict__ QKV, const float* __restrict__ sqk,
                  bf16* __restrict__ Qb, bf16* __restrict__ Kb, bf16* __restrict__ Vt)
{
    int gw   = (blockIdx.x * 256 + threadIdx.x) >> 6;   // 0 .. H*NROW-1
    int lane = threadIdx.x & 63;
    int h = gw / NROW, row = gw % NROW, t = row % T_, b = row / T_;

    const float* base = QKV + ((long)h * NROW + row) * 192;
    float q = base[lane], k = base[64 + lane], v = base[128 + lane];

    int   j   = lane & 31;
    float inv = expf(-(float)j * (9.210340371976184f / 32.f));  // 10000^(-j/32)
    float ang = (float)t * inv;
    float s = sinf(ang), c = cosf(ang);

    float qp = __shfl_xor(q, 32, 64);
    float kp = __shfl_xor(k, 32, 64);
    float sgn = (lane < 32) ? -1.f : 1.f;
    float qr = q * c + sgn * qp * s;
    float kr = k * c + sgn * kp * s;

    float qs = wave_sum(qr * qr);
    float ks = wave_sum(kr * kr);
    float se = sqk[h * 64 + lane] * 32.f;   // sqk * sqrt(dm)

    long idx = ((long)h * NROW + row) * 64 + lane;
    Qb[idx] = __float2bfloat16(qr * rsqrtf(qs) * se * 32.f);  // sdpa scale folded
    Kb[idx] = __float2bfloat16(kr * rsqrtf(ks) * se);
    Vt[((long)(h * B_ + b) * 64 + lane) * T_ + t] = __float2bfloat16(v);
}

// ---------------------------------------------------------------------------
// MFMA flash attention. One wave = 16 queries; stream 64-key tiles from L2.
// Swapped QK^T: S^T = mfma(K, Q)  -> D: row=key(4g+r), col=q(lane&15).
// PV: O^T = mfma(V^T, P^T)        -> D: row=d,        col=q.
// Q has sqk_eff and the sqrt(dm) sdpa scale pre-folded.
// ---------------------------------------------------------------------------
__global__ __launch_bounds__(256)
void attn_mfma(const bf16* __restrict__ Qb, const bf16* __restrict__ Kb,
               const bf16* __restrict__ Vt, float* __restrict__ O)
{
    // work-balanced mapping: block j of (h,b) pairs short & long q-tiles
    int j  = blockIdx.x & 31;           // 0..31
    int hb = blockIdx.x >> 5;           // 0..63
    int h  = hb >> 2, b = hb & 3;
    int w  = threadIdx.x >> 6;          // wave in block
    int qt = w * 32 + j;                // 0..127
    int q0 = qt * 16;

    int lane = threadIdx.x & 63;
    int g = lane >> 4, c = lane & 15;

    const bf16* qbase = Qb + ((long)h * NROW + (long)b * T_ + q0) * 64;
    const bf16* kbase = Kb + ((long)h * NROW + (long)b * T_) * 64;
    const bf16* vbase = Vt + (long)(h * B_ + b) * 64 * (long)T_;

    // Q B-frags: lane holds Q[q=c][d = 8g+j], halves d<32 / d>=32
    bfrag qf0 = *(const bfrag*)(qbase + (long)c * 64 + 8 * g);
    bfrag qf1 = *(const bfrag*)(qbase + (long)c * 64 + 32 + 8 * g);

    f4 ot[4] = {{0,0,0,0},{0,0,0,0},{0,0,0,0},{0,0,0,0}};
    float m = -1e30f, lsum = 0.f;

    int nfull = q0 >> 6;
    int qg = q0 + c;

    for (int kt = 0; kt <= nfull; kt++) {
        int k0 = kt * 64;
        bool maskt = (kt == nfull);

        // ---- QK^T: 4 key-blocks of 16, K-dim 64 = 2 mfmas each ----
        f4 s[4];
#pragma unroll
        for (int kb = 0; kb < 4; kb++) {
            const bf16* kr = kbase + (long)(k0 + 16 * kb + c) * 64 + 8 * g;
            bfrag ka = *(const bfrag*)kr;
            bfrag kc = *(const bfrag*)(kr + 32);
            f4 acc = {0, 0, 0, 0};
            acc = __builtin_amdgcn_mfma_f32_16x16x32_bf16(ka, qf0, acc, 0, 0, 0);
            acc = __builtin_amdgcn_mfma_f32_16x16x32_bf16(kc, qf1, acc, 0, 0, 0);
            s[kb] = acc;
        }
        if (maskt) {
#pragma unroll
            for (int kb = 0; kb < 4; kb++)
#pragma unroll
                for (int r = 0; r < 4; r++) {
                    int kg = k0 + 16 * kb + 4 * g + r;
                    if (kg > qg) s[kb][r] = -1e30f;
                }
        }

        // ---- online softmax (state per q=c, replicated over groups) ----
        float tmax = s[0][0];
#pragma unroll
        for (int kb = 0; kb < 4; kb++)
#pragma unroll
            for (int r = 0; r < 4; r++) tmax = fmaxf(tmax, s[kb][r]);
        tmax = fmaxf(tmax, __shfl_xor(tmax, 16, 64));
        tmax = fmaxf(tmax, __shfl_xor(tmax, 32, 64));
        float mn   = fmaxf(m, tmax);
        float corr = __expf(m - mn);

        float psum = 0.f;
        unsigned wv[8];
#pragma unroll
        for (int kb = 0; kb < 4; kb++) {
            float e0 = __expf(s[kb][0] - mn);
            float e1 = __expf(s[kb][1] - mn);
            float e2 = __expf(s[kb][2] - mn);
            float e3 = __expf(s[kb][3] - mn);
            psum += (e0 + e1) + (e2 + e3);
            wv[2 * kb]     = pk2(e0, e1);
            wv[2 * kb + 1] = pk2(e2, e3);
        }
        psum += __shfl_xor(psum, 16, 64);
        psum += __shfl_xor(psum, 32, 64);
        lsum = lsum * corr + psum;
        m = mn;
#pragma unroll
        for (int i = 0; i < 4; i++) ot[i] *= corr;

        // ---- PV: two 32-key halves; B-frag = P^T via lane exchange ----
#pragma unroll
        for (int p = 0; p < 2; p++) {
            int s0l = c + 32 * (g & 1), s1l = s0l + 16;
            unsigned a0 = (unsigned)__shfl((int)wv[4 * p + 0], s0l, 64);
            unsigned a1 = (unsigned)__shfl((int)wv[4 * p + 1], s0l, 64);
            unsigned b0 = (unsigned)__shfl((int)wv[4 * p + 2], s0l, 64);
            unsigned b1 = (unsigned)__shfl((int)wv[4 * p + 3], s0l, 64);
            unsigned a2 = (unsigned)__shfl((int)wv[4 * p + 0], s1l, 64);
            unsigned a3 = (unsigned)__shfl((int)wv[4 * p + 1], s1l, 64);
            unsigned b2 = (unsigned)__shfl((int)wv[4 * p + 2], s1l, 64);
            unsigned b3 = (unsigned)__shfl((int)wv[4 * p + 3], s1l, 64);
            bool hi = (g >= 2);
            union { bfrag f; unsigned u[4]; } pf;
            pf.u[0] = hi ? b0 : a0;
            pf.u[1] = hi ? b1 : a1;
            pf.u[2] = hi ? b2 : a2;
            pf.u[3] = hi ? b3 : a3;
#pragma unroll
            for (int dblk = 0; dblk < 4; dblk++) {
                const bf16* vr = vbase + (long)(16 * dblk + c) * T_ + (k0 + 32 * p + 8 * g);
                bfrag vf = *(const bfrag*)vr;
                ot[dblk] = __builtin_amdgcn_mfma_f32_16x16x32_bf16(vf, pf.f, ot[dblk], 0, 0, 0);
            }
        }
    }

    float inv = 1.f / lsum;
    long orow = (long)(b * T_ + q0 + c) * DM + h * 64;
#pragma unroll
    for (int dblk = 0; dblk < 4; dblk++)
#pragma unroll
        for (int r = 0; r < 4; r++)
            O[orow + 16 * dblk + 4 * g + r] = ot[dblk][r] * inv;
}

// ---------------------------------------------------------------------------
__global__ __launch_bounds__(256)
void lerp_norm(const float* __restrict__ X, const float* __restrict__ Tt,
               const float* __restrict__ alpha, float ascale, float* __restrict__ Out)
{
    long row = blockIdx.x;
    const float* xr = X  + row * DM;
    const float* tr = Tt + row * DM;
    int tid = threadIdx.x;

    float xs[4], ts[4], sx = 0.f, st = 0.f;
#pragma unroll
    for (int i = 0; i < 4; i++) {
        int d = tid + 256 * i;
        xs[i] = xr[d]; ts[i] = tr[d];
        sx += xs[i] * xs[i]; st += ts[i] * ts[i];
    }
    sx = block_sum(sx);
    st = block_sum(st);
    float ix = rsqrtf(sx), it = rsqrtf(st);

    float ys[4], sy = 0.f;
#pragma unroll
    for (int i = 0; i < 4; i++) {
        int d = tid + 256 * i;
        float a  = xs[i] * ix;
        float bn = ts[i] * it;
        float lr = fabsf(alpha[d] * ascale);
        ys[i] = a + lr * (bn - a);
        sy += ys[i] * ys[i];
    }
    sy = block_sum(sy);
    float iy = rsqrtf(sy);
#pragma unroll
    for (int i = 0; i < 4; i++) {
        int d = tid + 256 * i;
        Out[row * DM + d] = ys[i] * iy;
    }
}

// ---------------------------------------------------------------------------
__global__ __launch_bounds__(256)
void mlp_act(const bf16* __restrict__ UV, const float* __restrict__ suv,
             bf16* __restrict__ R)
{
    long row = blockIdx.x;
    const bf16* ur = UV + row * 8192;
    int tid = threadIdx.x;

    float ss = 0.f;
#pragma unroll
    for (int i = 0; i < 32; i++) {
        int j = tid + 256 * i;
        float v = __bfloat162float(ur[j]) * suv[j] * 32.f;
        ss += v * v;
    }
    ss = block_sum(ss);
    float inv = rsqrtf(ss);

#pragma unroll
    for (int i = 0; i < 16; i++) {
        int j = tid + 256 * i;
        float u = __bfloat162float(ur[j])        * suv[j]        * 32.f * inv;
        float v = __bfloat162float(ur[4096 + j]) * suv[4096 + j] * 32.f * inv;
        float sil = v / (1.f + __expf(-v));
        R[row * 4096 + j] = __float2bfloat16(u * sil);
    }
}

// ---------------------------------------------------------------------------
extern "C" void kernel_launch(void* const* d_in, const int* in_sizes, int n_in,
                              void* d_out, int out_size, void* d_ws, size_t ws_size,
                              hipStream_t stream)
{
    const float* x          = (const float*)d_in[0];
    const float* qkv_w      = (const float*)d_in[1];
    const float* sqk        = (const float*)d_in[2];
    const float* W_O        = (const float*)d_in[3];
    const float* Wu         = (const float*)d_in[4];
    const float* Wv         = (const float*)d_in[5];
    const float* attn_alpha = (const float*)d_in[6];
    const float* mlp_alpha  = (const float*)d_in[7];
    const float* suv        = (const float*)d_in[8];
    float* out = (float*)d_out;

    char* ws = (char*)d_ws;
    float* x1    = (float*)(ws + 0);
    float* QKV   = (float*)(ws + 33554432);
    float* attno = (float*)(ws + 134217728);
    bf16*  Qb    = (bf16*) (ws + 167772160);
    bf16*  Kb    = (bf16*) (ws + 184549376);
    bf16*  Vt    = (bf16*) (ws + 201326592);
    float* tbuf  = (float*)(ws + 167772160);
    bf16*  uv    = (bf16*) (ws + 33554432);
    bf16*  res   = (bf16*) (ws + 167772160);
    float* t2    = (float*)(ws + 33554432);
    // requires ws_size >= 234881024 bytes

    // 1) per-head QKV projection
    gemm_nt<float, float, float><<<dim3(3, 128, 16), 256, 0, stream>>>(
        x, qkv_w, QKV, NROW, 192, DM, 0L, 192L * 1024, (long)NROW * 192);

    // 2) RoPE + justnorm + scaling -> bf16 Qb/Kb/Vt
    rope_norm_qk<<<(H_ * NROW) / 4, 256, 0, stream>>>(QKV, sqk, Qb, Kb, Vt);

    // 3) MFMA flash attention
    attn_mfma<<<2048, 256, 0, stream>>>(Qb, Kb, Vt, attno);

    // 4) W_O projection
    gemm_nt<float, float, float><<<dim3(16, 128, 1), 256, 0, stream>>>(
        attno, W_O, tbuf, NROW, DM, DM, 0L, 0L, 0L);

    // 5) attention residual lerp-norm -> x1
    lerp_norm<<<NROW, 256, 0, stream>>>(x, tbuf, attn_alpha, 1.6f, x1);

    // 6) uv = x1 @ Wu^T -> bf16
    gemm_nt<float, float, bf16><<<dim3(128, 128, 1), 256, 0, stream>>>(
        x1, Wu, uv, NROW, 8 * DM, DM, 0L, 0L, 0L);

    // 7) row-normalize(8192) + SwiGLU -> res bf16
    mlp_act<<<NROW, 256, 0, stream>>>(uv, suv, res);

    // 8) t2 = res @ Wv^T
    gemm_nt<bf16, float, float><<<dim3(16, 128, 1), 256, 0, stream>>>(
        res, Wv, t2, NROW, DM, 4 * DM, 0L, 0L, 0L);

    // 9) MLP residual lerp-norm -> out
    lerp_norm<<<NROW, 256, 0, stream>>>(x1, t2, mlp_alpha, 0.05f, out);
}

// Round 4
// 834.208 us; speedup vs baseline: 15.5940x; 4.8902x over previous
//
#include <hip/hip_runtime.h>
#include <hip/hip_bf16.h>

// nGPT-style transformer layer, MI355X. Round 3: bf16 MFMA GEMMs (m97 pattern).
// B=4 T=2048 dm=1024 H=16 di=64.
//
// Workspace arena (peak 210 MiB). Aliasing is ORDER-SENSITIVE; launch order in
// kernel_launch is the contract:
//   [0,  32M)  x1    fp32 [8192][1024]        (lerp1 -> end)
//   [32, 48M)  x1b   bf16 [8192][1024]        (lerp1 -> Wu gemm)
//   [48,144M)  QKV   fp32 [8192][3072]        (qkv gemm -> rope)
//   [48, 80M)  tbuf  fp32 [8192][1024]        (W_O gemm -> lerp1; after QKV dead)
//   [48,112M)  uv    bf16 [4096][8192] half   (Wu gemm -> mlp_act, reused 2x)
//   [48, 80M)  t2    fp32 [8192][1024]        (Wv gemm -> lerp2; after uv dead)
//   [144,160M) xb    bf16 [8192][1024]        (convert -> qkv gemm)
//   [144,160M) Qb    bf16 [16][8192][64]      (rope -> attn; after xb dead)
//   [144,160M) Wub   bf16 [8192][1024]        (convert after attn -> Wu gemm2;
//                                              clobbered by res half2 after)
//   [160,176M) Kb    bf16 [16][8192][64]      (rope -> attn)
//   [176,192M) Vt    bf16 [16][4][64][2048]   (rope -> attn)
//   [176,184M) Wvb   bf16 [1024][4096]        (convert after attn -> Wv gemm)
//   [112,176M) res   bf16 [8192][4096]        (mlp_act -> Wv gemm; half1 at
//                                              [112,144) before Wub dead)
//   [192,198M) qkvwb bf16 [3072][1024]        (convert -> qkv gemm)
//   [192,208M) attno bf16 [8192][1024]        (attn -> W_O gemm; after qkvwb)
//   [208,210M) Wob   bf16 [1024][1024]        (convert -> W_O gemm)

#define B_   4
#define T_   2048
#define DM   1024
#define H_   16
#define DI   64
#define NROW (B_ * T_)   // 8192

using bf16 = __hip_bfloat16;
typedef __attribute__((ext_vector_type(8))) short bfrag;   // 8 bf16 (4 VGPR)
typedef __attribute__((ext_vector_type(4))) float f4;

__device__ __forceinline__ void  stf(float* p, float v) { *p = v; }
__device__ __forceinline__ void  stf(bf16* p, float v)  { *p = __float2bfloat16(v); }

__device__ __forceinline__ unsigned short bfbits(float a) {
    bf16 h = __float2bfloat16(a);
    return __builtin_bit_cast(unsigned short, h);
}
__device__ __forceinline__ unsigned pk2(float a, float b) {
    return (unsigned)bfbits(a) | ((unsigned)bfbits(b) << 16);
}

__device__ __forceinline__ float wave_sum(float v) {
#pragma unroll
    for (int off = 32; off; off >>= 1) v += __shfl_xor(v, off, 64);
    return v;
}

__device__ __forceinline__ float block_sum(float v) {
    __shared__ float sm[4];
    int lane = threadIdx.x & 63, w = threadIdx.x >> 6;
    v = wave_sum(v);
    __syncthreads();
    if (lane == 0) sm[w] = v;
    __syncthreads();
    return sm[0] + sm[1] + sm[2] + sm[3];
}

// async global->LDS, 16B per lane; LDS dest = wave-uniform base + lane*16
typedef __attribute__((address_space(1))) const void g_void;
typedef __attribute__((address_space(3))) void l_void;
__device__ __forceinline__ void gl_lds(const void* g, void* l) {
    __builtin_amdgcn_global_load_lds((g_void*)g, (l_void*)l, 16, 0, 0);
}

// ---------------------------------------------------------------------------
// f32 -> bf16 convert, 8 elems/thread. n must be a multiple of 2048.
// ---------------------------------------------------------------------------
__global__ __launch_bounds__(256)
void f32_to_bf16_k(const float* __restrict__ in, bf16* __restrict__ out, long n)
{
    long i = ((long)blockIdx.x * 256 + threadIdx.x) * 8;
    if (i >= n) return;
    float4 a = *(const float4*)(in + i);
    float4 b = *(const float4*)(in + i + 4);
    union { bfrag f; unsigned u[4]; } o;
    o.u[0] = pk2(a.x, a.y); o.u[1] = pk2(a.z, a.w);
    o.u[2] = pk2(b.x, b.y); o.u[3] = pk2(b.z, b.w);
    *(bfrag*)(out + i) = o.f;
}

// ---------------------------------------------------------------------------
// C = A * B^T, A[M][K], B[N][K] bf16 row-major. 128x128 tile, BK=32, 4 waves,
// m97 structure: global_load_lds(16B) double-buffered staging, 8 ds_read_b128
// + 16 mfma_16x16x32 per K-step per wave. M,N %128==0, K %32==0.
// ---------------------------------------------------------------------------
template <typename TC>
__global__ __launch_bounds__(256)
void gemm_bf16(const bf16* __restrict__ A, const bf16* __restrict__ Bm,
               TC* __restrict__ C, int M, int N, int K)
{
    __shared__ bf16 lds[2][2][128 * 32];   // [buf][A|B][row*32+k]
    const int tid  = threadIdx.x;
    const int w    = tid >> 6, lane = tid & 63;
    const int g    = lane >> 4, c = lane & 15;
    const int m0   = blockIdx.y * 128, n0 = blockIdx.x * 128;
    const int wm   = w >> 1, wn = w & 1;

    const int srow = (lane >> 2);        // 0..15 within chunk
    const int skc  = 8 * (lane & 3);     // k elem offset 0,8,16,24

    f4 acc[4][4] = {{{0,0,0,0}}};

    const int NT = K >> 5;               // K/32 steps

    // prologue: stage tile 0 into buf 0
#pragma unroll
    for (int q = 0; q < 2; q++) {
        int cidx = w * 2 + q;            // 0..7, covers rows [16*cidx,+16)
        int row  = 16 * cidx + srow;
        gl_lds(A + (long)(m0 + row) * K + skc, &lds[0][0][cidx * 512]);
        gl_lds(Bm + (long)(n0 + row) * K + skc, &lds[0][1][cidx * 512]);
    }
    __syncthreads();

    for (int t = 0; t < NT; t++) {
        int cur = t & 1;
        if (t + 1 < NT) {
            int k0 = (t + 1) << 5;
#pragma unroll
            for (int q = 0; q < 2; q++) {
                int cidx = w * 2 + q;
                int row  = 16 * cidx + srow;
                gl_lds(A + (long)(m0 + row) * K + k0 + skc, &lds[cur ^ 1][0][cidx * 512]);
                gl_lds(Bm + (long)(n0 + row) * K + k0 + skc, &lds[cur ^ 1][1][cidx * 512]);
            }
        }
        const bf16* bufA = &lds[cur][0][0];
        const bf16* bufB = &lds[cur][1][0];
        bfrag af[4], bb[4];
#pragma unroll
        for (int mi = 0; mi < 4; mi++)
            af[mi] = *(const bfrag*)(bufA + (64 * wm + 16 * mi + c) * 32 + 8 * g);
#pragma unroll
        for (int ni = 0; ni < 4; ni++)
            bb[ni] = *(const bfrag*)(bufB + (64 * wn + 16 * ni + c) * 32 + 8 * g);
#pragma unroll
        for (int mi = 0; mi < 4; mi++)
#pragma unroll
            for (int ni = 0; ni < 4; ni++)
                acc[mi][ni] = __builtin_amdgcn_mfma_f32_16x16x32_bf16(
                    af[mi], bb[ni], acc[mi][ni], 0, 0, 0);
        __syncthreads();
    }

    // epilogue: D row = 4g+r (from A operand), col = c (from B operand)
#pragma unroll
    for (int mi = 0; mi < 4; mi++)
#pragma unroll
        for (int ni = 0; ni < 4; ni++) {
            long row = m0 + 64 * wm + 16 * mi + 4 * g;
            long col = n0 + 64 * wn + 16 * ni + c;
#pragma unroll
            for (int r = 0; r < 4; r++)
                stf(&C[(row + r) * N + col], acc[mi][ni][r]);
        }
}

// ---------------------------------------------------------------------------
// RoPE + per-row L2 norm + sqk*sqrt(dm); QKV layout [row][h*192+e].
// Emits bf16 Qb (sdpa scale folded), Kb, and Vt[h][b][d][T].
// ---------------------------------------------------------------------------
__global__ __launch_bounds__(256)
void rope_norm_qk(const float* __restrict__ QKV, const float* __restrict__ sqk,
                  bf16* __restrict__ Qb, bf16* __restrict__ Kb, bf16* __restrict__ Vt)
{
    int gw   = (blockIdx.x * 256 + threadIdx.x) >> 6;   // 0 .. H*NROW-1
    int lane = threadIdx.x & 63;
    int h = gw / NROW, row = gw % NROW, t = row % T_, b = row / T_;

    const float* base = QKV + (long)row * 3072 + h * 192;
    float q = base[lane], k = base[64 + lane], v = base[128 + lane];

    int   j   = lane & 31;
    float inv = expf(-(float)j * (9.210340371976184f / 32.f));  // 10000^(-j/32)
    float ang = (float)t * inv;
    float s = sinf(ang), cc = cosf(ang);

    float qp = __shfl_xor(q, 32, 64);
    float kp = __shfl_xor(k, 32, 64);
    float sgn = (lane < 32) ? -1.f : 1.f;
    float qr = q * cc + sgn * qp * s;
    float kr = k * cc + sgn * kp * s;

    float qs = wave_sum(qr * qr);
    float ks = wave_sum(kr * kr);
    float se = sqk[h * 64 + lane] * 32.f;   // sqk * sqrt(dm)

    long idx = ((long)h * NROW + row) * 64 + lane;
    Qb[idx] = __float2bfloat16(qr * rsqrtf(qs) * se * 32.f);  // sdpa scale folded
    Kb[idx] = __float2bfloat16(kr * rsqrtf(ks) * se);
    Vt[((long)(h * B_ + b) * 64 + lane) * T_ + t] = __float2bfloat16(v);
}

// ---------------------------------------------------------------------------
// MFMA flash attention; one wave = 16 queries; bf16 output [row][h*64+d].
// ---------------------------------------------------------------------------
__global__ __launch_bounds__(256)
void attn_mfma(const bf16* __restrict__ Qb, const bf16* __restrict__ Kb,
               const bf16* __restrict__ Vt, bf16* __restrict__ O)
{
    int j  = blockIdx.x & 31;
    int hb = blockIdx.x >> 5;
    int h  = hb >> 2, b = hb & 3;
    int w  = threadIdx.x >> 6;
    int qt = w * 32 + j;
    int q0 = qt * 16;

    int lane = threadIdx.x & 63;
    int g = lane >> 4, c = lane & 15;

    const bf16* qbase = Qb + ((long)h * NROW + (long)b * T_ + q0) * 64;
    const bf16* kbase = Kb + ((long)h * NROW + (long)b * T_) * 64;
    const bf16* vbase = Vt + (long)(h * B_ + b) * 64 * (long)T_;

    bfrag qf0 = *(const bfrag*)(qbase + (long)c * 64 + 8 * g);
    bfrag qf1 = *(const bfrag*)(qbase + (long)c * 64 + 32 + 8 * g);

    f4 ot[4] = {{0,0,0,0},{0,0,0,0},{0,0,0,0},{0,0,0,0}};
    float m = -1e30f, lsum = 0.f;

    int nfull = q0 >> 6;
    int qg = q0 + c;

    for (int kt = 0; kt <= nfull; kt++) {
        int k0 = kt * 64;
        bool maskt = (kt == nfull);

        f4 s[4];
#pragma unroll
        for (int kb = 0; kb < 4; kb++) {
            const bf16* kr = kbase + (long)(k0 + 16 * kb + c) * 64 + 8 * g;
            bfrag ka = *(const bfrag*)kr;
            bfrag kc = *(const bfrag*)(kr + 32);
            f4 acc = {0, 0, 0, 0};
            acc = __builtin_amdgcn_mfma_f32_16x16x32_bf16(ka, qf0, acc, 0, 0, 0);
            acc = __builtin_amdgcn_mfma_f32_16x16x32_bf16(kc, qf1, acc, 0, 0, 0);
            s[kb] = acc;
        }
        if (maskt) {
#pragma unroll
            for (int kb = 0; kb < 4; kb++)
#pragma unroll
                for (int r = 0; r < 4; r++) {
                    int kg = k0 + 16 * kb + 4 * g + r;
                    if (kg > qg) s[kb][r] = -1e30f;
                }
        }

        float tmax = s[0][0];
#pragma unroll
        for (int kb = 0; kb < 4; kb++)
#pragma unroll
            for (int r = 0; r < 4; r++) tmax = fmaxf(tmax, s[kb][r]);
        tmax = fmaxf(tmax, __shfl_xor(tmax, 16, 64));
        tmax = fmaxf(tmax, __shfl_xor(tmax, 32, 64));
        float mn   = fmaxf(m, tmax);
        float corr = __expf(m - mn);

        float psum = 0.f;
        unsigned wv[8];
#pragma unroll
        for (int kb = 0; kb < 4; kb++) {
            float e0 = __expf(s[kb][0] - mn);
            float e1 = __expf(s[kb][1] - mn);
            float e2 = __expf(s[kb][2] - mn);
            float e3 = __expf(s[kb][3] - mn);
            psum += (e0 + e1) + (e2 + e3);
            wv[2 * kb]     = pk2(e0, e1);
            wv[2 * kb + 1] = pk2(e2, e3);
        }
        psum += __shfl_xor(psum, 16, 64);
        psum += __shfl_xor(psum, 32, 64);
        lsum = lsum * corr + psum;
        m = mn;
#pragma unroll
        for (int i = 0; i < 4; i++) ot[i] *= corr;

#pragma unroll
        for (int p = 0; p < 2; p++) {
            int s0l = c + 32 * (g & 1), s1l = s0l + 16;
            unsigned a0 = (unsigned)__shfl((int)wv[4 * p + 0], s0l, 64);
            unsigned a1 = (unsigned)__shfl((int)wv[4 * p + 1], s0l, 64);
            unsigned b0 = (unsigned)__shfl((int)wv[4 * p + 2], s0l, 64);
            unsigned b1 = (unsigned)__shfl((int)wv[4 * p + 3], s0l, 64);
            unsigned a2 = (unsigned)__shfl((int)wv[4 * p + 0], s1l, 64);
            unsigned a3 = (unsigned)__shfl((int)wv[4 * p + 1], s1l, 64);
            unsigned b2 = (unsigned)__shfl((int)wv[4 * p + 2], s1l, 64);
            unsigned b3 = (unsigned)__shfl((int)wv[4 * p + 3], s1l, 64);
            bool hi = (g >= 2);
            union { bfrag f; unsigned u[4]; } pf;
            pf.u[0] = hi ? b0 : a0;
            pf.u[1] = hi ? b1 : a1;
            pf.u[2] = hi ? b2 : a2;
            pf.u[3] = hi ? b3 : a3;
#pragma unroll
            for (int dblk = 0; dblk < 4; dblk++) {
                const bf16* vr = vbase + (long)(16 * dblk + c) * T_ + (k0 + 32 * p + 8 * g);
                bfrag vf = *(const bfrag*)vr;
                ot[dblk] = __builtin_amdgcn_mfma_f32_16x16x32_bf16(vf, pf.f, ot[dblk], 0, 0, 0);
            }
        }
    }

    float inv = 1.f / lsum;
    long orow = (long)(b * T_ + q0 + c) * DM + h * 64;
#pragma unroll
    for (int dblk = 0; dblk < 4; dblk++)
#pragma unroll
        for (int r = 0; r < 4; r++)
            O[orow + 16 * dblk + 4 * g + r] = __float2bfloat16(ot[dblk][r] * inv);
}

// ---------------------------------------------------------------------------
__global__ __launch_bounds__(256)
void lerp_norm(const float* __restrict__ X, const float* __restrict__ Tt,
               const float* __restrict__ alpha, float ascale,
               float* __restrict__ Out, bf16* __restrict__ OutB)
{
    long row = blockIdx.x;
    const float* xr = X  + row * DM;
    const float* tr = Tt + row * DM;
    int tid = threadIdx.x;

    float xs[4], ts[4], sx = 0.f, st = 0.f;
#pragma unroll
    for (int i = 0; i < 4; i++) {
        int d = tid + 256 * i;
        xs[i] = xr[d]; ts[i] = tr[d];
        sx += xs[i] * xs[i]; st += ts[i] * ts[i];
    }
    sx = block_sum(sx);
    st = block_sum(st);
    float ix = rsqrtf(sx), it = rsqrtf(st);

    float ys[4], sy = 0.f;
#pragma unroll
    for (int i = 0; i < 4; i++) {
        int d = tid + 256 * i;
        float a  = xs[i] * ix;
        float bn = ts[i] * it;
        float lr = fabsf(alpha[d] * ascale);
        ys[i] = a + lr * (bn - a);
        sy += ys[i] * ys[i];
    }
    sy = block_sum(sy);
    float iy = rsqrtf(sy);
#pragma unroll
    for (int i = 0; i < 4; i++) {
        int d = tid + 256 * i;
        float o = ys[i] * iy;
        Out[row * DM + d] = o;
        if (OutB) OutB[row * DM + d] = __float2bfloat16(o);
    }
}

// ---------------------------------------------------------------------------
__global__ __launch_bounds__(256)
void mlp_act(const bf16* __restrict__ UV, const float* __restrict__ suv,
             bf16* __restrict__ R)
{
    long row = blockIdx.x;
    const bf16* ur = UV + row * 8192;
    int tid = threadIdx.x;

    float ss = 0.f;
#pragma unroll
    for (int i = 0; i < 32; i++) {
        int j = tid + 256 * i;
        float v = __bfloat162float(ur[j]) * suv[j] * 32.f;
        ss += v * v;
    }
    ss = block_sum(ss);
    float inv = rsqrtf(ss);

#pragma unroll
    for (int i = 0; i < 16; i++) {
        int j = tid + 256 * i;
        float u = __bfloat162float(ur[j])        * suv[j]        * 32.f * inv;
        float v = __bfloat162float(ur[4096 + j]) * suv[4096 + j] * 32.f * inv;
        float sil = v / (1.f + __expf(-v));
        R[row * 4096 + j] = __float2bfloat16(u * sil);
    }
}

// ---------------------------------------------------------------------------
extern "C" void kernel_launch(void* const* d_in, const int* in_sizes, int n_in,
                              void* d_out, int out_size, void* d_ws, size_t ws_size,
                              hipStream_t stream)
{
    const float* x          = (const float*)d_in[0];
    const float* qkv_w      = (const float*)d_in[1];
    const float* sqk        = (const float*)d_in[2];
    const float* W_O        = (const float*)d_in[3];
    const float* Wu         = (const float*)d_in[4];
    const float* Wv         = (const float*)d_in[5];
    const float* attn_alpha = (const float*)d_in[6];
    const float* mlp_alpha  = (const float*)d_in[7];
    const float* suv        = (const float*)d_in[8];
    float* out = (float*)d_out;

    const long MiB = 1048576;
    char* ws = (char*)d_ws;
    float* x1    = (float*)(ws + 0 * MiB);
    bf16*  x1b   = (bf16*) (ws + 32 * MiB);
    float* QKV   = (float*)(ws + 48 * MiB);
    float* tbuf  = (float*)(ws + 48 * MiB);
    bf16*  uv    = (bf16*) (ws + 48 * MiB);   // half: [4096][8192]
    float* t2    = (float*)(ws + 48 * MiB);
    bf16*  xb    = (bf16*) (ws + 144 * MiB);
    bf16*  Qb    = (bf16*) (ws + 144 * MiB);
    bf16*  Wub   = (bf16*) (ws + 144 * MiB);
    bf16*  Kb    = (bf16*) (ws + 160 * MiB);
    bf16*  Vt    = (bf16*) (ws + 176 * MiB);
    bf16*  Wvb   = (bf16*) (ws + 176 * MiB);
    bf16*  res   = (bf16*) (ws + 112 * MiB);  // [8192][4096]
    bf16*  qkvwb = (bf16*) (ws + 192 * MiB);
    bf16*  attno = (bf16*) (ws + 192 * MiB);
    bf16*  Wob   = (bf16*) (ws + 208 * MiB);
    // peak 210 MiB

    // 0) converts needed before attn
    f32_to_bf16_k<<<4096, 256, 0, stream>>>(x, xb, 8388608L);
    f32_to_bf16_k<<<1536, 256, 0, stream>>>(qkv_w, qkvwb, 3145728L);
    f32_to_bf16_k<<<512,  256, 0, stream>>>(W_O, Wob, 1048576L);

    // 1) QKV projection: [8192][1024] x [3072][1024]^T -> fp32 [8192][3072]
    gemm_bf16<float><<<dim3(24, 64), 256, 0, stream>>>(xb, qkvwb, QKV, NROW, 3072, DM);

    // 2) RoPE + justnorm + scaling -> Qb/Kb/Vt
    rope_norm_qk<<<(H_ * NROW) / 4, 256, 0, stream>>>(QKV, sqk, Qb, Kb, Vt);

    // 3) MFMA flash attention -> attno bf16 (overwrites qkvwb region)
    attn_mfma<<<2048, 256, 0, stream>>>(Qb, Kb, Vt, attno);

    // 4) W_O projection -> tbuf fp32 (QKV region dead)
    gemm_bf16<float><<<dim3(8, 64), 256, 0, stream>>>(attno, Wob, tbuf, NROW, DM, DM);

    // 5) attention residual lerp-norm -> x1 fp32 + x1b bf16
    lerp_norm<<<NROW, 256, 0, stream>>>(x, tbuf, attn_alpha, 1.6f, x1, x1b);

    // 6) weight converts for MLP (Qb/Kb/Vt dead)
    f32_to_bf16_k<<<4096, 256, 0, stream>>>(Wu, Wub, 8388608L);
    f32_to_bf16_k<<<2048, 256, 0, stream>>>(Wv, Wvb, 4194304L);

    // 7) MLP in two M-halves: uv(half) = x1b @ Wu^T -> bf16; act -> res
    for (int half = 0; half < 2; half++) {
        gemm_bf16<bf16><<<dim3(64, 32), 256, 0, stream>>>(
            x1b + (long)half * 4096 * DM, Wub, uv, 4096, 8 * DM, DM);
        mlp_act<<<4096, 256, 0, stream>>>(uv, suv, res + (long)half * 4096 * 4096);
    }
    // note: mlp_act(half2) clobbers Wub region — Wub dead by then.

    // 8) t2 = res @ Wv^T -> fp32 (uv dead)
    gemm_bf16<float><<<dim3(8, 64), 256, 0, stream>>>(res, Wvb, t2, NROW, DM, 4 * DM);

    // 9) MLP residual lerp-norm -> out
    lerp_norm<<<NROW, 256, 0, stream>>>(x1, t2, mlp_alpha, 0.05f, out, (bf16*)nullptr);
}

// Round 5
// 743.527 us; speedup vs baseline: 17.4958x; 1.1220x over previous
//
#include <hip/hip_runtime.h>
#include <hip/hip_bf16.h>

// nGPT-style transformer layer, MI355X. Round 4: attention XCD-swizzle +
// work-pairing; QKV projection output in bf16.
// B=4 T=2048 dm=1024 H=16 di=64.
//
// Workspace arena (peak 210 MiB). Aliasing is ORDER-SENSITIVE; launch order in
// kernel_launch is the contract:
//   [0,  32M)  x1    fp32 [8192][1024]        (lerp1 -> end)
//   [32, 48M)  x1b   bf16 [8192][1024]        (lerp1 -> Wu gemm)
//   [48, 96M)  QKVb  bf16 [8192][3072]        (qkv gemm -> rope)
//   [48, 80M)  tbuf  fp32 [8192][1024]        (W_O gemm -> lerp1; QKVb dead)
//   [48,112M)  uv    bf16 [4096][8192] half   (Wu gemm -> mlp_act, reused 2x)
//   [48, 80M)  t2    fp32 [8192][1024]        (Wv gemm -> lerp2; uv dead)
//   [144,160M) xb    bf16 [8192][1024]        (convert -> qkv gemm)
//   [144,160M) Qb    bf16 [16][8192][64]      (rope -> attn; after xb dead)
//   [144,160M) Wub   bf16 [8192][1024]        (convert after attn -> Wu gemm2;
//                                              clobbered by res half2 after)
//   [160,176M) Kb    bf16 [16][8192][64]      (rope -> attn)
//   [176,192M) Vt    bf16 [16][4][64][2048]   (rope -> attn)
//   [176,184M) Wvb   bf16 [1024][4096]        (convert after attn -> Wv gemm)
//   [112,176M) res   bf16 [8192][4096]        (mlp_act -> Wv gemm)
//   [192,198M) qkvwb bf16 [3072][1024]        (convert -> qkv gemm)
//   [192,208M) attno bf16 [8192][1024]        (attn -> W_O gemm; after qkvwb)
//   [208,210M) Wob   bf16 [1024][1024]        (convert -> W_O gemm)

#define B_   4
#define T_   2048
#define DM   1024
#define H_   16
#define DI   64
#define NROW (B_ * T_)   // 8192

using bf16 = __hip_bfloat16;
typedef __attribute__((ext_vector_type(8))) short bfrag;   // 8 bf16 (4 VGPR)
typedef __attribute__((ext_vector_type(4))) float f4;

__device__ __forceinline__ void  stf(float* p, float v) { *p = v; }
__device__ __forceinline__ void  stf(bf16* p, float v)  { *p = __float2bfloat16(v); }

__device__ __forceinline__ unsigned short bfbits(float a) {
    bf16 h = __float2bfloat16(a);
    return __builtin_bit_cast(unsigned short, h);
}
__device__ __forceinline__ unsigned pk2(float a, float b) {
    return (unsigned)bfbits(a) | ((unsigned)bfbits(b) << 16);
}

__device__ __forceinline__ float wave_sum(float v) {
#pragma unroll
    for (int off = 32; off; off >>= 1) v += __shfl_xor(v, off, 64);
    return v;
}

__device__ __forceinline__ float block_sum(float v) {
    __shared__ float sm[4];
    int lane = threadIdx.x & 63, w = threadIdx.x >> 6;
    v = wave_sum(v);
    __syncthreads();
    if (lane == 0) sm[w] = v;
    __syncthreads();
    return sm[0] + sm[1] + sm[2] + sm[3];
}

// async global->LDS, 16B per lane; LDS dest = wave-uniform base + lane*16
typedef __attribute__((address_space(1))) const void g_void;
typedef __attribute__((address_space(3))) void l_void;
__device__ __forceinline__ void gl_lds(const void* g, void* l) {
    __builtin_amdgcn_global_load_lds((g_void*)g, (l_void*)l, 16, 0, 0);
}

// ---------------------------------------------------------------------------
// f32 -> bf16 convert, 8 elems/thread. n must be a multiple of 2048.
// ---------------------------------------------------------------------------
__global__ __launch_bounds__(256)
void f32_to_bf16_k(const float* __restrict__ in, bf16* __restrict__ out, long n)
{
    long i = ((long)blockIdx.x * 256 + threadIdx.x) * 8;
    if (i >= n) return;
    float4 a = *(const float4*)(in + i);
    float4 b = *(const float4*)(in + i + 4);
    union { bfrag f; unsigned u[4]; } o;
    o.u[0] = pk2(a.x, a.y); o.u[1] = pk2(a.z, a.w);
    o.u[2] = pk2(b.x, b.y); o.u[3] = pk2(b.z, b.w);
    *(bfrag*)(out + i) = o.f;
}

// ---------------------------------------------------------------------------
// C = A * B^T, A[M][K], B[N][K] bf16 row-major. 128x128 tile, BK=32, 4 waves,
// m97 structure: global_load_lds(16B) double-buffered staging, 8 ds_read_b128
// + 16 mfma_16x16x32 per K-step per wave. M,N %128==0, K %32==0.
// ---------------------------------------------------------------------------
template <typename TC>
__global__ __launch_bounds__(256)
void gemm_bf16(const bf16* __restrict__ A, const bf16* __restrict__ Bm,
               TC* __restrict__ C, int M, int N, int K)
{
    __shared__ bf16 lds[2][2][128 * 32];   // [buf][A|B][row*32+k]
    const int tid  = threadIdx.x;
    const int w    = tid >> 6, lane = tid & 63;
    const int g    = lane >> 4, c = lane & 15;
    const int m0   = blockIdx.y * 128, n0 = blockIdx.x * 128;
    const int wm   = w >> 1, wn = w & 1;

    const int srow = (lane >> 2);        // 0..15 within chunk
    const int skc  = 8 * (lane & 3);     // k elem offset 0,8,16,24

    f4 acc[4][4] = {{{0,0,0,0}}};

    const int NT = K >> 5;               // K/32 steps

#pragma unroll
    for (int q = 0; q < 2; q++) {
        int cidx = w * 2 + q;            // 0..7, covers rows [16*cidx,+16)
        int row  = 16 * cidx + srow;
        gl_lds(A + (long)(m0 + row) * K + skc, &lds[0][0][cidx * 512]);
        gl_lds(Bm + (long)(n0 + row) * K + skc, &lds[0][1][cidx * 512]);
    }
    __syncthreads();

    for (int t = 0; t < NT; t++) {
        int cur = t & 1;
        if (t + 1 < NT) {
            int k0 = (t + 1) << 5;
#pragma unroll
            for (int q = 0; q < 2; q++) {
                int cidx = w * 2 + q;
                int row  = 16 * cidx + srow;
                gl_lds(A + (long)(m0 + row) * K + k0 + skc, &lds[cur ^ 1][0][cidx * 512]);
                gl_lds(Bm + (long)(n0 + row) * K + k0 + skc, &lds[cur ^ 1][1][cidx * 512]);
            }
        }
        const bf16* bufA = &lds[cur][0][0];
        const bf16* bufB = &lds[cur][1][0];
        bfrag af[4], bb[4];
#pragma unroll
        for (int mi = 0; mi < 4; mi++)
            af[mi] = *(const bfrag*)(bufA + (64 * wm + 16 * mi + c) * 32 + 8 * g);
#pragma unroll
        for (int ni = 0; ni < 4; ni++)
            bb[ni] = *(const bfrag*)(bufB + (64 * wn + 16 * ni + c) * 32 + 8 * g);
#pragma unroll
        for (int mi = 0; mi < 4; mi++)
#pragma unroll
            for (int ni = 0; ni < 4; ni++)
                acc[mi][ni] = __builtin_amdgcn_mfma_f32_16x16x32_bf16(
                    af[mi], bb[ni], acc[mi][ni], 0, 0, 0);
        __syncthreads();
    }

#pragma unroll
    for (int mi = 0; mi < 4; mi++)
#pragma unroll
        for (int ni = 0; ni < 4; ni++) {
            long row = m0 + 64 * wm + 16 * mi + 4 * g;
            long col = n0 + 64 * wn + 16 * ni + c;
#pragma unroll
            for (int r = 0; r < 4; r++)
                stf(&C[(row + r) * N + col], acc[mi][ni][r]);
        }
}

// ---------------------------------------------------------------------------
// RoPE + per-row L2 norm + sqk*sqrt(dm); QKVb bf16 layout [row][h*192+e].
// Emits bf16 Qb (sdpa scale folded), Kb, and Vt[h][b][d][T].
// ---------------------------------------------------------------------------
__global__ __launch_bounds__(256)
void rope_norm_qk(const bf16* __restrict__ QKVb, const float* __restrict__ sqk,
                  bf16* __restrict__ Qb, bf16* __restrict__ Kb, bf16* __restrict__ Vt)
{
    int gw   = (blockIdx.x * 256 + threadIdx.x) >> 6;   // 0 .. H*NROW-1
    int lane = threadIdx.x & 63;
    int h = gw / NROW, row = gw % NROW, t = row % T_, b = row / T_;

    const bf16* base = QKVb + (long)row * 3072 + h * 192;
    float q = __bfloat162float(base[lane]);
    float k = __bfloat162float(base[64 + lane]);
    bf16  v = base[128 + lane];

    int   j   = lane & 31;
    float inv = expf(-(float)j * (9.210340371976184f / 32.f));  // 10000^(-j/32)
    float ang = (float)t * inv;
    float s = sinf(ang), cc = cosf(ang);

    float qp = __shfl_xor(q, 32, 64);
    float kp = __shfl_xor(k, 32, 64);
    float sgn = (lane < 32) ? -1.f : 1.f;
    float qr = q * cc + sgn * qp * s;
    float kr = k * cc + sgn * kp * s;

    float qs = wave_sum(qr * qr);
    float ks = wave_sum(kr * kr);
    float se = sqk[h * 64 + lane] * 32.f;   // sqk * sqrt(dm)

    long idx = ((long)h * NROW + row) * 64 + lane;
    Qb[idx] = __float2bfloat16(qr * rsqrtf(qs) * se * 32.f);  // sdpa scale folded
    Kb[idx] = __float2bfloat16(kr * rsqrtf(ks) * se);
    Vt[((long)(h * B_ + b) * 64 + lane) * T_ + t] = v;
}

// ---------------------------------------------------------------------------
// MFMA flash attention; one wave = two 16-query tiles (pr and 127-pr, equal
// total work per wave). XCD-aware swizzle: blockIdx%8 = XCD owns 8 (h,b)
// pairs -> K/V working set 4 MiB = per-XCD L2.
// ---------------------------------------------------------------------------
__global__ __launch_bounds__(256)
void attn_mfma(const bf16* __restrict__ Qb, const bf16* __restrict__ Kb,
               const bf16* __restrict__ Vt, bf16* __restrict__ O)
{
    int orig = blockIdx.x;            // 0..1023
    int xcd  = orig & 7;
    int rest = orig >> 3;             // 0..127
    int bh   = xcd * 8 + (rest & 7);  // 0..63
    int blk  = rest >> 3;             // 0..15
    int w    = threadIdx.x >> 6;
    int pr   = blk * 4 + w;           // 0..63 pair index
    int h = bh >> 2, b = bh & 3;

    int lane = threadIdx.x & 63;
    int g = lane >> 4, c = lane & 15;

    const bf16* kbase = Kb + ((long)h * NROW + (long)b * T_) * 64;
    const bf16* vbase = Vt + (long)(h * B_ + b) * 64 * (long)T_;

#pragma unroll 1
    for (int qi = 0; qi < 2; qi++) {
        int qt = qi ? (127 - pr) : pr;
        int q0 = qt * 16;

        const bf16* qbase = Qb + ((long)h * NROW + (long)b * T_ + q0) * 64;
        bfrag qf0 = *(const bfrag*)(qbase + (long)c * 64 + 8 * g);
        bfrag qf1 = *(const bfrag*)(qbase + (long)c * 64 + 32 + 8 * g);

        f4 ot[4] = {{0,0,0,0},{0,0,0,0},{0,0,0,0},{0,0,0,0}};
        float m = -1e30f, lsum = 0.f;

        int nfull = q0 >> 6;
        int qg = q0 + c;

        for (int kt = 0; kt <= nfull; kt++) {
            int k0 = kt * 64;
            bool maskt = (kt == nfull);

            f4 s[4];
#pragma unroll
            for (int kb = 0; kb < 4; kb++) {
                const bf16* kr = kbase + (long)(k0 + 16 * kb + c) * 64 + 8 * g;
                bfrag ka = *(const bfrag*)kr;
                bfrag kc = *(const bfrag*)(kr + 32);
                f4 acc = {0, 0, 0, 0};
                acc = __builtin_amdgcn_mfma_f32_16x16x32_bf16(ka, qf0, acc, 0, 0, 0);
                acc = __builtin_amdgcn_mfma_f32_16x16x32_bf16(kc, qf1, acc, 0, 0, 0);
                s[kb] = acc;
            }
            if (maskt) {
#pragma unroll
                for (int kb = 0; kb < 4; kb++)
#pragma unroll
                    for (int r = 0; r < 4; r++) {
                        int kg = k0 + 16 * kb + 4 * g + r;
                        if (kg > qg) s[kb][r] = -1e30f;
                    }
            }

            float tmax = s[0][0];
#pragma unroll
            for (int kb = 0; kb < 4; kb++)
#pragma unroll
                for (int r = 0; r < 4; r++) tmax = fmaxf(tmax, s[kb][r]);
            tmax = fmaxf(tmax, __shfl_xor(tmax, 16, 64));
            tmax = fmaxf(tmax, __shfl_xor(tmax, 32, 64));
            float mn   = fmaxf(m, tmax);
            float corr = __expf(m - mn);

            float psum = 0.f;
            unsigned wv[8];
#pragma unroll
            for (int kb = 0; kb < 4; kb++) {
                float e0 = __expf(s[kb][0] - mn);
                float e1 = __expf(s[kb][1] - mn);
                float e2 = __expf(s[kb][2] - mn);
                float e3 = __expf(s[kb][3] - mn);
                psum += (e0 + e1) + (e2 + e3);
                wv[2 * kb]     = pk2(e0, e1);
                wv[2 * kb + 1] = pk2(e2, e3);
            }
            psum += __shfl_xor(psum, 16, 64);
            psum += __shfl_xor(psum, 32, 64);
            lsum = lsum * corr + psum;
            m = mn;
#pragma unroll
            for (int i = 0; i < 4; i++) ot[i] *= corr;

#pragma unroll
            for (int p = 0; p < 2; p++) {
                int s0l = c + 32 * (g & 1), s1l = s0l + 16;
                unsigned a0 = (unsigned)__shfl((int)wv[4 * p + 0], s0l, 64);
                unsigned a1 = (unsigned)__shfl((int)wv[4 * p + 1], s0l, 64);
                unsigned b0 = (unsigned)__shfl((int)wv[4 * p + 2], s0l, 64);
                unsigned b1 = (unsigned)__shfl((int)wv[4 * p + 3], s0l, 64);
                unsigned a2 = (unsigned)__shfl((int)wv[4 * p + 0], s1l, 64);
                unsigned a3 = (unsigned)__shfl((int)wv[4 * p + 1], s1l, 64);
                unsigned b2 = (unsigned)__shfl((int)wv[4 * p + 2], s1l, 64);
                unsigned b3 = (unsigned)__shfl((int)wv[4 * p + 3], s1l, 64);
                bool hi = (g >= 2);
                union { bfrag f; unsigned u[4]; } pf;
                pf.u[0] = hi ? b0 : a0;
                pf.u[1] = hi ? b1 : a1;
                pf.u[2] = hi ? b2 : a2;
                pf.u[3] = hi ? b3 : a3;
#pragma unroll
                for (int dblk = 0; dblk < 4; dblk++) {
                    const bf16* vr = vbase + (long)(16 * dblk + c) * T_ + (k0 + 32 * p + 8 * g);
                    bfrag vf = *(const bfrag*)vr;
                    ot[dblk] = __builtin_amdgcn_mfma_f32_16x16x32_bf16(vf, pf.f, ot[dblk], 0, 0, 0);
                }
            }
        }

        float inv = 1.f / lsum;
        long orow = (long)(b * T_ + q0 + c) * DM + h * 64;
#pragma unroll
        for (int dblk = 0; dblk < 4; dblk++)
#pragma unroll
            for (int r = 0; r < 4; r++)
                O[orow + 16 * dblk + 4 * g + r] = __float2bfloat16(ot[dblk][r] * inv);
    }
}

// ---------------------------------------------------------------------------
__global__ __launch_bounds__(256)
void lerp_norm(const float* __restrict__ X, const float* __restrict__ Tt,
               const float* __restrict__ alpha, float ascale,
               float* __restrict__ Out, bf16* __restrict__ OutB)
{
    long row = blockIdx.x;
    const float* xr = X  + row * DM;
    const float* tr = Tt + row * DM;
    int tid = threadIdx.x;

    float xs[4], ts[4], sx = 0.f, st = 0.f;
#pragma unroll
    for (int i = 0; i < 4; i++) {
        int d = tid + 256 * i;
        xs[i] = xr[d]; ts[i] = tr[d];
        sx += xs[i] * xs[i]; st += ts[i] * ts[i];
    }
    sx = block_sum(sx);
    st = block_sum(st);
    float ix = rsqrtf(sx), it = rsqrtf(st);

    float ys[4], sy = 0.f;
#pragma unroll
    for (int i = 0; i < 4; i++) {
        int d = tid + 256 * i;
        float a  = xs[i] * ix;
        float bn = ts[i] * it;
        float lr = fabsf(alpha[d] * ascale);
        ys[i] = a + lr * (bn - a);
        sy += ys[i] * ys[i];
    }
    sy = block_sum(sy);
    float iy = rsqrtf(sy);
#pragma unroll
    for (int i = 0; i < 4; i++) {
        int d = tid + 256 * i;
        float o = ys[i] * iy;
        Out[row * DM + d] = o;
        if (OutB) OutB[row * DM + d] = __float2bfloat16(o);
    }
}

// ---------------------------------------------------------------------------
__global__ __launch_bounds__(256)
void mlp_act(const bf16* __restrict__ UV, const float* __restrict__ suv,
             bf16* __restrict__ R)
{
    long row = blockIdx.x;
    const bf16* ur = UV + row * 8192;
    int tid = threadIdx.x;

    float ss = 0.f;
#pragma unroll
    for (int i = 0; i < 32; i++) {
        int j = tid + 256 * i;
        float v = __bfloat162float(ur[j]) * suv[j] * 32.f;
        ss += v * v;
    }
    ss = block_sum(ss);
    float inv = rsqrtf(ss);

#pragma unroll
    for (int i = 0; i < 16; i++) {
        int j = tid + 256 * i;
        float u = __bfloat162float(ur[j])        * suv[j]        * 32.f * inv;
        float v = __bfloat162float(ur[4096 + j]) * suv[4096 + j] * 32.f * inv;
        float sil = v / (1.f + __expf(-v));
        R[row * 4096 + j] = __float2bfloat16(u * sil);
    }
}

// ---------------------------------------------------------------------------
extern "C" void kernel_launch(void* const* d_in, const int* in_sizes, int n_in,
                              void* d_out, int out_size, void* d_ws, size_t ws_size,
                              hipStream_t stream)
{
    const float* x          = (const float*)d_in[0];
    const float* qkv_w      = (const float*)d_in[1];
    const float* sqk        = (const float*)d_in[2];
    const float* W_O        = (const float*)d_in[3];
    const float* Wu         = (const float*)d_in[4];
    const float* Wv         = (const float*)d_in[5];
    const float* attn_alpha = (const float*)d_in[6];
    const float* mlp_alpha  = (const float*)d_in[7];
    const float* suv        = (const float*)d_in[8];
    float* out = (float*)d_out;

    const long MiB = 1048576;
    char* ws = (char*)d_ws;
    float* x1    = (float*)(ws + 0 * MiB);
    bf16*  x1b   = (bf16*) (ws + 32 * MiB);
    bf16*  QKVb  = (bf16*) (ws + 48 * MiB);
    float* tbuf  = (float*)(ws + 48 * MiB);
    bf16*  uv    = (bf16*) (ws + 48 * MiB);   // half: [4096][8192]
    float* t2    = (float*)(ws + 48 * MiB);
    bf16*  xb    = (bf16*) (ws + 144 * MiB);
    bf16*  Qb    = (bf16*) (ws + 144 * MiB);
    bf16*  Wub   = (bf16*) (ws + 144 * MiB);
    bf16*  Kb    = (bf16*) (ws + 160 * MiB);
    bf16*  Vt    = (bf16*) (ws + 176 * MiB);
    bf16*  Wvb   = (bf16*) (ws + 176 * MiB);
    bf16*  res   = (bf16*) (ws + 112 * MiB);  // [8192][4096]
    bf16*  qkvwb = (bf16*) (ws + 192 * MiB);
    bf16*  attno = (bf16*) (ws + 192 * MiB);
    bf16*  Wob   = (bf16*) (ws + 208 * MiB);
    // peak 210 MiB

    // 0) converts needed before attn
    f32_to_bf16_k<<<4096, 256, 0, stream>>>(x, xb, 8388608L);
    f32_to_bf16_k<<<1536, 256, 0, stream>>>(qkv_w, qkvwb, 3145728L);
    f32_to_bf16_k<<<512,  256, 0, stream>>>(W_O, Wob, 1048576L);

    // 1) QKV projection -> bf16 [8192][3072]
    gemm_bf16<bf16><<<dim3(24, 64), 256, 0, stream>>>(xb, qkvwb, QKVb, NROW, 3072, DM);

    // 2) RoPE + justnorm + scaling -> Qb/Kb/Vt
    rope_norm_qk<<<(H_ * NROW) / 4, 256, 0, stream>>>(QKVb, sqk, Qb, Kb, Vt);

    // 3) MFMA flash attention -> attno bf16 (overwrites qkvwb region)
    attn_mfma<<<1024, 256, 0, stream>>>(Qb, Kb, Vt, attno);

    // 4) W_O projection -> tbuf fp32 (QKVb region dead)
    gemm_bf16<float><<<dim3(8, 64), 256, 0, stream>>>(attno, Wob, tbuf, NROW, DM, DM);

    // 5) attention residual lerp-norm -> x1 fp32 + x1b bf16
    lerp_norm<<<NROW, 256, 0, stream>>>(x, tbuf, attn_alpha, 1.6f, x1, x1b);

    // 6) weight converts for MLP (Qb/Kb/Vt dead)
    f32_to_bf16_k<<<4096, 256, 0, stream>>>(Wu, Wub, 8388608L);
    f32_to_bf16_k<<<2048, 256, 0, stream>>>(Wv, Wvb, 4194304L);

    // 7) MLP in two M-halves: uv(half) = x1b @ Wu^T -> bf16; act -> res
    for (int half = 0; half < 2; half++) {
        gemm_bf16<bf16><<<dim3(64, 32), 256, 0, stream>>>(
            x1b + (long)half * 4096 * DM, Wub, uv, 4096, 8 * DM, DM);
        mlp_act<<<4096, 256, 0, stream>>>(uv, suv, res + (long)half * 4096 * 4096);
    }
    // note: mlp_act(half2) clobbers Wub region — Wub dead by then.

    // 8) t2 = res @ Wv^T -> fp32 (uv dead)
    gemm_bf16<float><<<dim3(8, 64), 256, 0, stream>>>(res, Wvb, t2, NROW, DM, 4 * DM);

    // 9) MLP residual lerp-norm -> out
    lerp_norm<<<NROW, 256, 0, stream>>>(x1, t2, mlp_alpha, 0.05f, out, (bf16*)nullptr);
}

// Round 6
// 723.669 us; speedup vs baseline: 17.9759x; 1.0274x over previous
//
#include <hip/hip_runtime.h>
#include <hip/hip_bf16.h>

// nGPT-style transformer layer, MI355X. Round 5: attention fixed-shift softmax
// (scores provably in [-32,32] -> no online max) + paired-q-tile interleave
// sharing K/V loads.
// B=4 T=2048 dm=1024 H=16 di=64.
//
// Workspace arena (peak 210 MiB). Aliasing is ORDER-SENSITIVE; launch order in
// kernel_launch is the contract:
//   [0,  32M)  x1    fp32 [8192][1024]        (lerp1 -> end)
//   [32, 48M)  x1b   bf16 [8192][1024]        (lerp1 -> Wu gemm)
//   [48, 96M)  QKVb  bf16 [8192][3072]        (qkv gemm -> rope)
//   [48, 80M)  tbuf  fp32 [8192][1024]        (W_O gemm -> lerp1; QKVb dead)
//   [48,112M)  uv    bf16 [4096][8192] half   (Wu gemm -> mlp_act, reused 2x)
//   [48, 80M)  t2    fp32 [8192][1024]        (Wv gemm -> lerp2; uv dead)
//   [144,160M) xb    bf16 [8192][1024]        (convert -> qkv gemm)
//   [144,160M) Qb    bf16 [16][8192][64]      (rope -> attn; after xb dead)
//   [144,160M) Wub   bf16 [8192][1024]        (convert after attn -> Wu gemm2;
//                                              clobbered by res half2 after)
//   [160,176M) Kb    bf16 [16][8192][64]      (rope -> attn)
//   [176,192M) Vt    bf16 [16][4][64][2048]   (rope -> attn)
//   [176,184M) Wvb   bf16 [1024][4096]        (convert after attn -> Wv gemm)
//   [112,176M) res   bf16 [8192][4096]        (mlp_act -> Wv gemm)
//   [192,198M) qkvwb bf16 [3072][1024]        (convert -> qkv gemm)
//   [192,208M) attno bf16 [8192][1024]        (attn -> W_O gemm; after qkvwb)
//   [208,210M) Wob   bf16 [1024][1024]        (convert -> W_O gemm)

#define B_   4
#define T_   2048
#define DM   1024
#define H_   16
#define DI   64
#define NROW (B_ * T_)   // 8192

using bf16 = __hip_bfloat16;
typedef __attribute__((ext_vector_type(8))) short bfrag;   // 8 bf16 (4 VGPR)
typedef __attribute__((ext_vector_type(4))) float f4;

__device__ __forceinline__ void  stf(float* p, float v) { *p = v; }
__device__ __forceinline__ void  stf(bf16* p, float v)  { *p = __float2bfloat16(v); }

__device__ __forceinline__ unsigned short bfbits(float a) {
    bf16 h = __float2bfloat16(a);
    return __builtin_bit_cast(unsigned short, h);
}
__device__ __forceinline__ unsigned pk2(float a, float b) {
    return (unsigned)bfbits(a) | ((unsigned)bfbits(b) << 16);
}

__device__ __forceinline__ float wave_sum(float v) {
#pragma unroll
    for (int off = 32; off; off >>= 1) v += __shfl_xor(v, off, 64);
    return v;
}

__device__ __forceinline__ float block_sum(float v) {
    __shared__ float sm[4];
    int lane = threadIdx.x & 63, w = threadIdx.x >> 6;
    v = wave_sum(v);
    __syncthreads();
    if (lane == 0) sm[w] = v;
    __syncthreads();
    return sm[0] + sm[1] + sm[2] + sm[3];
}

// async global->LDS, 16B per lane; LDS dest = wave-uniform base + lane*16
typedef __attribute__((address_space(1))) const void g_void;
typedef __attribute__((address_space(3))) void l_void;
__device__ __forceinline__ void gl_lds(const void* g, void* l) {
    __builtin_amdgcn_global_load_lds((g_void*)g, (l_void*)l, 16, 0, 0);
}

// ---------------------------------------------------------------------------
// f32 -> bf16 convert, 8 elems/thread. n must be a multiple of 2048.
// ---------------------------------------------------------------------------
__global__ __launch_bounds__(256)
void f32_to_bf16_k(const float* __restrict__ in, bf16* __restrict__ out, long n)
{
    long i = ((long)blockIdx.x * 256 + threadIdx.x) * 8;
    if (i >= n) return;
    float4 a = *(const float4*)(in + i);
    float4 b = *(const float4*)(in + i + 4);
    union { bfrag f; unsigned u[4]; } o;
    o.u[0] = pk2(a.x, a.y); o.u[1] = pk2(a.z, a.w);
    o.u[2] = pk2(b.x, b.y); o.u[3] = pk2(b.z, b.w);
    *(bfrag*)(out + i) = o.f;
}

// ---------------------------------------------------------------------------
// C = A * B^T, A[M][K], B[N][K] bf16 row-major. 128x128 tile, BK=32, 4 waves,
// m97 structure: global_load_lds(16B) double-buffered staging, 8 ds_read_b128
// + 16 mfma_16x16x32 per K-step per wave. M,N %128==0, K %32==0.
// ---------------------------------------------------------------------------
template <typename TC>
__global__ __launch_bounds__(256)
void gemm_bf16(const bf16* __restrict__ A, const bf16* __restrict__ Bm,
               TC* __restrict__ C, int M, int N, int K)
{
    __shared__ bf16 lds[2][2][128 * 32];   // [buf][A|B][row*32+k]
    const int tid  = threadIdx.x;
    const int w    = tid >> 6, lane = tid & 63;
    const int g    = lane >> 4, c = lane & 15;
    const int m0   = blockIdx.y * 128, n0 = blockIdx.x * 128;
    const int wm   = w >> 1, wn = w & 1;

    const int srow = (lane >> 2);        // 0..15 within chunk
    const int skc  = 8 * (lane & 3);     // k elem offset 0,8,16,24

    f4 acc[4][4] = {{{0,0,0,0}}};

    const int NT = K >> 5;               // K/32 steps

#pragma unroll
    for (int q = 0; q < 2; q++) {
        int cidx = w * 2 + q;            // 0..7, covers rows [16*cidx,+16)
        int row  = 16 * cidx + srow;
        gl_lds(A + (long)(m0 + row) * K + skc, &lds[0][0][cidx * 512]);
        gl_lds(Bm + (long)(n0 + row) * K + skc, &lds[0][1][cidx * 512]);
    }
    __syncthreads();

    for (int t = 0; t < NT; t++) {
        int cur = t & 1;
        if (t + 1 < NT) {
            int k0 = (t + 1) << 5;
#pragma unroll
            for (int q = 0; q < 2; q++) {
                int cidx = w * 2 + q;
                int row  = 16 * cidx + srow;
                gl_lds(A + (long)(m0 + row) * K + k0 + skc, &lds[cur ^ 1][0][cidx * 512]);
                gl_lds(Bm + (long)(n0 + row) * K + k0 + skc, &lds[cur ^ 1][1][cidx * 512]);
            }
        }
        const bf16* bufA = &lds[cur][0][0];
        const bf16* bufB = &lds[cur][1][0];
        bfrag af[4], bb[4];
#pragma unroll
        for (int mi = 0; mi < 4; mi++)
            af[mi] = *(const bfrag*)(bufA + (64 * wm + 16 * mi + c) * 32 + 8 * g);
#pragma unroll
        for (int ni = 0; ni < 4; ni++)
            bb[ni] = *(const bfrag*)(bufB + (64 * wn + 16 * ni + c) * 32 + 8 * g);
#pragma unroll
        for (int mi = 0; mi < 4; mi++)
#pragma unroll
            for (int ni = 0; ni < 4; ni++)
                acc[mi][ni] = __builtin_amdgcn_mfma_f32_16x16x32_bf16(
                    af[mi], bb[ni], acc[mi][ni], 0, 0, 0);
        __syncthreads();
    }

#pragma unroll
    for (int mi = 0; mi < 4; mi++)
#pragma unroll
        for (int ni = 0; ni < 4; ni++) {
            long row = m0 + 64 * wm + 16 * mi + 4 * g;
            long col = n0 + 64 * wn + 16 * ni + c;
#pragma unroll
            for (int r = 0; r < 4; r++)
                stf(&C[(row + r) * N + col], acc[mi][ni][r]);
        }
}

// ---------------------------------------------------------------------------
// RoPE + per-row L2 norm + sqk*sqrt(dm); QKVb bf16 layout [row][h*192+e].
// Emits bf16 Qb (sdpa scale folded), Kb, and Vt[h][b][d][T].
// ---------------------------------------------------------------------------
__global__ __launch_bounds__(256)
void rope_norm_qk(const bf16* __restrict__ QKVb, const float* __restrict__ sqk,
                  bf16* __restrict__ Qb, bf16* __restrict__ Kb, bf16* __restrict__ Vt)
{
    int gw   = (blockIdx.x * 256 + threadIdx.x) >> 6;   // 0 .. H*NROW-1
    int lane = threadIdx.x & 63;
    int h = gw / NROW, row = gw % NROW, t = row % T_, b = row / T_;

    const bf16* base = QKVb + (long)row * 3072 + h * 192;
    float q = __bfloat162float(base[lane]);
    float k = __bfloat162float(base[64 + lane]);
    bf16  v = base[128 + lane];

    int   j   = lane & 31;
    float inv = expf(-(float)j * (9.210340371976184f / 32.f));  // 10000^(-j/32)
    float ang = (float)t * inv;
    float s = sinf(ang), cc = cosf(ang);

    float qp = __shfl_xor(q, 32, 64);
    float kp = __shfl_xor(k, 32, 64);
    float sgn = (lane < 32) ? -1.f : 1.f;
    float qr = q * cc + sgn * qp * s;
    float kr = k * cc + sgn * kp * s;

    float qs = wave_sum(qr * qr);
    float ks = wave_sum(kr * kr);
    float se = sqk[h * 64 + lane] * 32.f;   // sqk * sqrt(dm)

    long idx = ((long)h * NROW + row) * 64 + lane;
    Qb[idx] = __float2bfloat16(qr * rsqrtf(qs) * se * 32.f);  // sdpa scale folded
    Kb[idx] = __float2bfloat16(kr * rsqrtf(ks) * se);
    Vt[((long)(h * B_ + b) * 64 + lane) * T_ + t] = v;
}

// ---------------------------------------------------------------------------
// MFMA flash attention, fixed-shift softmax. |Q row| = 32 (unit norm x
// sqk_eff=1 x folded sqrt(dm)=32), |K row| = 1 => scores in [-32,32], so
// exp(s-32) in [e^-64,1]: no online max, no rescale (softmax shift-invariant).
// One wave = two q-tiles (pr, 127-pr) interleaved in one k-loop, SHARING the
// K and V fragment loads (2x ILP on the serial softmax chain).
// XCD swizzle: blockIdx%8 = XCD owns 8 (h,b) pairs -> K/V set = 4MiB = L2.
// ---------------------------------------------------------------------------
__global__ __launch_bounds__(256)
void attn_mfma(const bf16* __restrict__ Qb, const bf16* __restrict__ Kb,
               const bf16* __restrict__ Vt, bf16* __restrict__ O)
{
    int orig = blockIdx.x;            // 0..1023
    int xcd  = orig & 7;
    int rest = orig >> 3;             // 0..127
    int bh   = xcd * 8 + (rest & 7);  // 0..63
    int blk  = rest >> 3;             // 0..15
    int w    = threadIdx.x >> 6;
    int pr   = blk * 4 + w;           // 0..63 pair index
    int h = bh >> 2, b = bh & 3;

    int lane = threadIdx.x & 63;
    int g = lane >> 4, c = lane & 15;

    const bf16* kbase = Kb + ((long)h * NROW + (long)b * T_) * 64;
    const bf16* vbase = Vt + (long)(h * B_ + b) * 64 * (long)T_;

    int q0A = pr * 16, q0B = (127 - pr) * 16;
    const bf16* qbA = Qb + ((long)h * NROW + (long)b * T_ + q0A) * 64;
    const bf16* qbB = Qb + ((long)h * NROW + (long)b * T_ + q0B) * 64;
    bfrag qfA0 = *(const bfrag*)(qbA + (long)c * 64 + 8 * g);
    bfrag qfA1 = *(const bfrag*)(qbA + (long)c * 64 + 32 + 8 * g);
    bfrag qfB0 = *(const bfrag*)(qbB + (long)c * 64 + 8 * g);
    bfrag qfB1 = *(const bfrag*)(qbB + (long)c * 64 + 32 + 8 * g);

    f4 otA[4] = {{0,0,0,0},{0,0,0,0},{0,0,0,0},{0,0,0,0}};
    f4 otB[4] = {{0,0,0,0},{0,0,0,0},{0,0,0,0},{0,0,0,0}};
    float lA = 0.f, lB = 0.f;

    int nA = q0A >> 6, nB = q0B >> 6;
    int qgA = q0A + c, qgB = q0B + c;

    for (int kt = 0; kt <= nB; kt++) {
        int k0 = kt * 64;
        bool actA = (kt <= nA);
        unsigned wvA[8], wvB[8];

#pragma unroll
        for (int kb = 0; kb < 4; kb++) {
            const bf16* kr = kbase + (long)(k0 + 16 * kb + c) * 64 + 8 * g;
            bfrag ka = *(const bfrag*)kr;
            bfrag kc = *(const bfrag*)(kr + 32);

            f4 sB = {0, 0, 0, 0};
            sB = __builtin_amdgcn_mfma_f32_16x16x32_bf16(ka, qfB0, sB, 0, 0, 0);
            sB = __builtin_amdgcn_mfma_f32_16x16x32_bf16(kc, qfB1, sB, 0, 0, 0);
            if (kt == nB) {
#pragma unroll
                for (int r = 0; r < 4; r++)
                    if (k0 + 16 * kb + 4 * g + r > qgB) sB[r] = -1e30f;
            }
            float eB0 = __expf(sB[0] - 32.f), eB1 = __expf(sB[1] - 32.f);
            float eB2 = __expf(sB[2] - 32.f), eB3 = __expf(sB[3] - 32.f);
            lB += (eB0 + eB1) + (eB2 + eB3);
            wvB[2 * kb]     = pk2(eB0, eB1);
            wvB[2 * kb + 1] = pk2(eB2, eB3);

            if (actA) {
                f4 sA = {0, 0, 0, 0};
                sA = __builtin_amdgcn_mfma_f32_16x16x32_bf16(ka, qfA0, sA, 0, 0, 0);
                sA = __builtin_amdgcn_mfma_f32_16x16x32_bf16(kc, qfA1, sA, 0, 0, 0);
                if (kt == nA) {
#pragma unroll
                    for (int r = 0; r < 4; r++)
                        if (k0 + 16 * kb + 4 * g + r > qgA) sA[r] = -1e30f;
                }
                float eA0 = __expf(sA[0] - 32.f), eA1 = __expf(sA[1] - 32.f);
                float eA2 = __expf(sA[2] - 32.f), eA3 = __expf(sA[3] - 32.f);
                lA += (eA0 + eA1) + (eA2 + eA3);
                wvA[2 * kb]     = pk2(eA0, eA1);
                wvA[2 * kb + 1] = pk2(eA2, eA3);
            }
        }

        // PV: two 32-key halves; B-frag = P^T via lane exchange; V shared
#pragma unroll
        for (int p = 0; p < 2; p++) {
            int s0l = c + 32 * (g & 1), s1l = s0l + 16;
            bool hi = (g >= 2);

            unsigned Bb0 = (unsigned)__shfl((int)wvB[4 * p + 0], s0l, 64);
            unsigned Bb1 = (unsigned)__shfl((int)wvB[4 * p + 1], s0l, 64);
            unsigned Bb2 = (unsigned)__shfl((int)wvB[4 * p + 2], s0l, 64);
            unsigned Bb3 = (unsigned)__shfl((int)wvB[4 * p + 3], s0l, 64);
            unsigned Bb4 = (unsigned)__shfl((int)wvB[4 * p + 0], s1l, 64);
            unsigned Bb5 = (unsigned)__shfl((int)wvB[4 * p + 1], s1l, 64);
            unsigned Bb6 = (unsigned)__shfl((int)wvB[4 * p + 2], s1l, 64);
            unsigned Bb7 = (unsigned)__shfl((int)wvB[4 * p + 3], s1l, 64);
            union { bfrag f; unsigned u[4]; } pfB;
            pfB.u[0] = hi ? Bb2 : Bb0;
            pfB.u[1] = hi ? Bb3 : Bb1;
            pfB.u[2] = hi ? Bb6 : Bb4;
            pfB.u[3] = hi ? Bb7 : Bb5;

            union { bfrag f; unsigned u[4]; } pfA;
            if (actA) {
                unsigned Ab0 = (unsigned)__shfl((int)wvA[4 * p + 0], s0l, 64);
                unsigned Ab1 = (unsigned)__shfl((int)wvA[4 * p + 1], s0l, 64);
                unsigned Ab2 = (unsigned)__shfl((int)wvA[4 * p + 2], s0l, 64);
                unsigned Ab3 = (unsigned)__shfl((int)wvA[4 * p + 3], s0l, 64);
                unsigned Ab4 = (unsigned)__shfl((int)wvA[4 * p + 0], s1l, 64);
                unsigned Ab5 = (unsigned)__shfl((int)wvA[4 * p + 1], s1l, 64);
                unsigned Ab6 = (unsigned)__shfl((int)wvA[4 * p + 2], s1l, 64);
                unsigned Ab7 = (unsigned)__shfl((int)wvA[4 * p + 3], s1l, 64);
                pfA.u[0] = hi ? Ab2 : Ab0;
                pfA.u[1] = hi ? Ab3 : Ab1;
                pfA.u[2] = hi ? Ab6 : Ab4;
                pfA.u[3] = hi ? Ab7 : Ab5;
            }

#pragma unroll
            for (int dblk = 0; dblk < 4; dblk++) {
                const bf16* vr = vbase + (long)(16 * dblk + c) * T_ + (k0 + 32 * p + 8 * g);
                bfrag vf = *(const bfrag*)vr;
                otB[dblk] = __builtin_amdgcn_mfma_f32_16x16x32_bf16(vf, pfB.f, otB[dblk], 0, 0, 0);
                if (actA)
                    otA[dblk] = __builtin_amdgcn_mfma_f32_16x16x32_bf16(vf, pfA.f, otA[dblk], 0, 0, 0);
            }
        }
    }

    // l reduction across the 4 lane-groups (deferred from per-tile to once)
    lA += __shfl_xor(lA, 16, 64); lA += __shfl_xor(lA, 32, 64);
    lB += __shfl_xor(lB, 16, 64); lB += __shfl_xor(lB, 32, 64);

    float invA = 1.f / lA, invB = 1.f / lB;
    long orowA = (long)(b * T_ + q0A + c) * DM + h * 64;
    long orowB = (long)(b * T_ + q0B + c) * DM + h * 64;
#pragma unroll
    for (int dblk = 0; dblk < 4; dblk++)
#pragma unroll
        for (int r = 0; r < 4; r++) {
            O[orowA + 16 * dblk + 4 * g + r] = __float2bfloat16(otA[dblk][r] * invA);
            O[orowB + 16 * dblk + 4 * g + r] = __float2bfloat16(otB[dblk][r] * invB);
        }
}

// ---------------------------------------------------------------------------
__global__ __launch_bounds__(256)
void lerp_norm(const float* __restrict__ X, const float* __restrict__ Tt,
               const float* __restrict__ alpha, float ascale,
               float* __restrict__ Out, bf16* __restrict__ OutB)
{
    long row = blockIdx.x;
    const float* xr = X  + row * DM;
    const float* tr = Tt + row * DM;
    int tid = threadIdx.x;

    float xs[4], ts[4], sx = 0.f, st = 0.f;
#pragma unroll
    for (int i = 0; i < 4; i++) {
        int d = tid + 256 * i;
        xs[i] = xr[d]; ts[i] = tr[d];
        sx += xs[i] * xs[i]; st += ts[i] * ts[i];
    }
    sx = block_sum(sx);
    st = block_sum(st);
    float ix = rsqrtf(sx), it = rsqrtf(st);

    float ys[4], sy = 0.f;
#pragma unroll
    for (int i = 0; i < 4; i++) {
        int d = tid + 256 * i;
        float a  = xs[i] * ix;
        float bn = ts[i] * it;
        float lr = fabsf(alpha[d] * ascale);
        ys[i] = a + lr * (bn - a);
        sy += ys[i] * ys[i];
    }
    sy = block_sum(sy);
    float iy = rsqrtf(sy);
#pragma unroll
    for (int i = 0; i < 4; i++) {
        int d = tid + 256 * i;
        float o = ys[i] * iy;
        Out[row * DM + d] = o;
        if (OutB) OutB[row * DM + d] = __float2bfloat16(o);
    }
}

// ---------------------------------------------------------------------------
__global__ __launch_bounds__(256)
void mlp_act(const bf16* __restrict__ UV, const float* __restrict__ suv,
             bf16* __restrict__ R)
{
    long row = blockIdx.x;
    const bf16* ur = UV + row * 8192;
    int tid = threadIdx.x;

    float ss = 0.f;
#pragma unroll
    for (int i = 0; i < 32; i++) {
        int j = tid + 256 * i;
        float v = __bfloat162float(ur[j]) * suv[j] * 32.f;
        ss += v * v;
    }
    ss = block_sum(ss);
    float inv = rsqrtf(ss);

#pragma unroll
    for (int i = 0; i < 16; i++) {
        int j = tid + 256 * i;
        float u = __bfloat162float(ur[j])        * suv[j]        * 32.f * inv;
        float v = __bfloat162float(ur[4096 + j]) * suv[4096 + j] * 32.f * inv;
        float sil = v / (1.f + __expf(-v));
        R[row * 4096 + j] = __float2bfloat16(u * sil);
    }
}

// ---------------------------------------------------------------------------
extern "C" void kernel_launch(void* const* d_in, const int* in_sizes, int n_in,
                              void* d_out, int out_size, void* d_ws, size_t ws_size,
                              hipStream_t stream)
{
    const float* x          = (const float*)d_in[0];
    const float* qkv_w      = (const float*)d_in[1];
    const float* sqk        = (const float*)d_in[2];
    const float* W_O        = (const float*)d_in[3];
    const float* Wu         = (const float*)d_in[4];
    const float* Wv         = (const float*)d_in[5];
    const float* attn_alpha = (const float*)d_in[6];
    const float* mlp_alpha  = (const float*)d_in[7];
    const float* suv        = (const float*)d_in[8];
    float* out = (float*)d_out;

    const long MiB = 1048576;
    char* ws = (char*)d_ws;
    float* x1    = (float*)(ws + 0 * MiB);
    bf16*  x1b   = (bf16*) (ws + 32 * MiB);
    bf16*  QKVb  = (bf16*) (ws + 48 * MiB);
    float* tbuf  = (float*)(ws + 48 * MiB);
    bf16*  uv    = (bf16*) (ws + 48 * MiB);   // half: [4096][8192]
    float* t2    = (float*)(ws + 48 * MiB);
    bf16*  xb    = (bf16*) (ws + 144 * MiB);
    bf16*  Qb    = (bf16*) (ws + 144 * MiB);
    bf16*  Wub   = (bf16*) (ws + 144 * MiB);
    bf16*  Kb    = (bf16*) (ws + 160 * MiB);
    bf16*  Vt    = (bf16*) (ws + 176 * MiB);
    bf16*  Wvb   = (bf16*) (ws + 176 * MiB);
    bf16*  res   = (bf16*) (ws + 112 * MiB);  // [8192][4096]
    bf16*  qkvwb = (bf16*) (ws + 192 * MiB);
    bf16*  attno = (bf16*) (ws + 192 * MiB);
    bf16*  Wob   = (bf16*) (ws + 208 * MiB);
    // peak 210 MiB

    // 0) converts needed before attn
    f32_to_bf16_k<<<4096, 256, 0, stream>>>(x, xb, 8388608L);
    f32_to_bf16_k<<<1536, 256, 0, stream>>>(qkv_w, qkvwb, 3145728L);
    f32_to_bf16_k<<<512,  256, 0, stream>>>(W_O, Wob, 1048576L);

    // 1) QKV projection -> bf16 [8192][3072]
    gemm_bf16<bf16><<<dim3(24, 64), 256, 0, stream>>>(xb, qkvwb, QKVb, NROW, 3072, DM);

    // 2) RoPE + justnorm + scaling -> Qb/Kb/Vt
    rope_norm_qk<<<(H_ * NROW) / 4, 256, 0, stream>>>(QKVb, sqk, Qb, Kb, Vt);

    // 3) MFMA flash attention -> attno bf16 (overwrites qkvwb region)
    attn_mfma<<<1024, 256, 0, stream>>>(Qb, Kb, Vt, attno);

    // 4) W_O projection -> tbuf fp32 (QKVb region dead)
    gemm_bf16<float><<<dim3(8, 64), 256, 0, stream>>>(attno, Wob, tbuf, NROW, DM, DM);

    // 5) attention residual lerp-norm -> x1 fp32 + x1b bf16
    lerp_norm<<<NROW, 256, 0, stream>>>(x, tbuf, attn_alpha, 1.6f, x1, x1b);

    // 6) weight converts for MLP (Qb/Kb/Vt dead)
    f32_to_bf16_k<<<4096, 256, 0, stream>>>(Wu, Wub, 8388608L);
    f32_to_bf16_k<<<2048, 256, 0, stream>>>(Wv, Wvb, 4194304L);

    // 7) MLP in two M-halves: uv(half) = x1b @ Wu^T -> bf16; act -> res
    for (int half = 0; half < 2; half++) {
        gemm_bf16<bf16><<<dim3(64, 32), 256, 0, stream>>>(
            x1b + (long)half * 4096 * DM, Wub, uv, 4096, 8 * DM, DM);
        mlp_act<<<4096, 256, 0, stream>>>(uv, suv, res + (long)half * 4096 * 4096);
    }
    // note: mlp_act(half2) clobbers Wub region — Wub dead by then.

    // 8) t2 = res @ Wv^T -> fp32 (uv dead)
    gemm_bf16<float><<<dim3(8, 64), 256, 0, stream>>>(res, Wvb, t2, NROW, DM, 4 * DM);

    // 9) MLP residual lerp-norm -> out
    lerp_norm<<<NROW, 256, 0, stream>>>(x1, t2, mlp_alpha, 0.05f, out, (bf16*)nullptr);
}

// Round 7
// 612.523 us; speedup vs baseline: 21.2378x; 1.1815x over previous
//
#include <hip/hip_runtime.h>
#include <hip/hip_bf16.h>

// nGPT-style transformer layer, MI355X. Round 6: attention K/V LDS staging
// (shared across 4 waves, double-buffered, XOR-swizzled via pre-swizzled
// global source). Fixed-shift softmax + paired q-tiles retained.
// B=4 T=2048 dm=1024 H=16 di=64.
//
// Workspace arena (peak 210 MiB). Aliasing is ORDER-SENSITIVE; launch order in
// kernel_launch is the contract (same as round 5).

#define B_   4
#define T_   2048
#define DM   1024
#define H_   16
#define DI   64
#define NROW (B_ * T_)   // 8192

using bf16 = __hip_bfloat16;
typedef __attribute__((ext_vector_type(8))) short bfrag;   // 8 bf16 (4 VGPR)
typedef __attribute__((ext_vector_type(4))) float f4;

__device__ __forceinline__ void  stf(float* p, float v) { *p = v; }
__device__ __forceinline__ void  stf(bf16* p, float v)  { *p = __float2bfloat16(v); }

__device__ __forceinline__ unsigned short bfbits(float a) {
    bf16 h = __float2bfloat16(a);
    return __builtin_bit_cast(unsigned short, h);
}
__device__ __forceinline__ unsigned pk2(float a, float b) {
    return (unsigned)bfbits(a) | ((unsigned)bfbits(b) << 16);
}

__device__ __forceinline__ float wave_sum(float v) {
#pragma unroll
    for (int off = 32; off; off >>= 1) v += __shfl_xor(v, off, 64);
    return v;
}

__device__ __forceinline__ float block_sum(float v) {
    __shared__ float sm[4];
    int lane = threadIdx.x & 63, w = threadIdx.x >> 6;
    v = wave_sum(v);
    __syncthreads();
    if (lane == 0) sm[w] = v;
    __syncthreads();
    return sm[0] + sm[1] + sm[2] + sm[3];
}

// async global->LDS, 16B per lane; LDS dest = wave-uniform base + lane*16
typedef __attribute__((address_space(1))) const void g_void;
typedef __attribute__((address_space(3))) void l_void;
__device__ __forceinline__ void gl_lds(const void* g, void* l) {
    __builtin_amdgcn_global_load_lds((g_void*)g, (l_void*)l, 16, 0, 0);
}

// ---------------------------------------------------------------------------
// f32 -> bf16 convert, 8 elems/thread. n must be a multiple of 2048.
// ---------------------------------------------------------------------------
__global__ __launch_bounds__(256)
void f32_to_bf16_k(const float* __restrict__ in, bf16* __restrict__ out, long n)
{
    long i = ((long)blockIdx.x * 256 + threadIdx.x) * 8;
    if (i >= n) return;
    float4 a = *(const float4*)(in + i);
    float4 b = *(const float4*)(in + i + 4);
    union { bfrag f; unsigned u[4]; } o;
    o.u[0] = pk2(a.x, a.y); o.u[1] = pk2(a.z, a.w);
    o.u[2] = pk2(b.x, b.y); o.u[3] = pk2(b.z, b.w);
    *(bfrag*)(out + i) = o.f;
}

// ---------------------------------------------------------------------------
// C = A * B^T, A[M][K], B[N][K] bf16 row-major. 128x128 tile, BK=32, 4 waves,
// m97 structure. M,N %128==0, K %32==0.
// ---------------------------------------------------------------------------
template <typename TC>
__global__ __launch_bounds__(256)
void gemm_bf16(const bf16* __restrict__ A, const bf16* __restrict__ Bm,
               TC* __restrict__ C, int M, int N, int K)
{
    __shared__ bf16 lds[2][2][128 * 32];   // [buf][A|B][row*32+k]
    const int tid  = threadIdx.x;
    const int w    = tid >> 6, lane = tid & 63;
    const int g    = lane >> 4, c = lane & 15;
    const int m0   = blockIdx.y * 128, n0 = blockIdx.x * 128;
    const int wm   = w >> 1, wn = w & 1;

    const int srow = (lane >> 2);        // 0..15 within chunk
    const int skc  = 8 * (lane & 3);     // k elem offset 0,8,16,24

    f4 acc[4][4] = {{{0,0,0,0}}};

    const int NT = K >> 5;               // K/32 steps

#pragma unroll
    for (int q = 0; q < 2; q++) {
        int cidx = w * 2 + q;            // 0..7, covers rows [16*cidx,+16)
        int row  = 16 * cidx + srow;
        gl_lds(A + (long)(m0 + row) * K + skc, &lds[0][0][cidx * 512]);
        gl_lds(Bm + (long)(n0 + row) * K + skc, &lds[0][1][cidx * 512]);
    }
    __syncthreads();

    for (int t = 0; t < NT; t++) {
        int cur = t & 1;
        if (t + 1 < NT) {
            int k0 = (t + 1) << 5;
#pragma unroll
            for (int q = 0; q < 2; q++) {
                int cidx = w * 2 + q;
                int row  = 16 * cidx + srow;
                gl_lds(A + (long)(m0 + row) * K + k0 + skc, &lds[cur ^ 1][0][cidx * 512]);
                gl_lds(Bm + (long)(n0 + row) * K + k0 + skc, &lds[cur ^ 1][1][cidx * 512]);
            }
        }
        const bf16* bufA = &lds[cur][0][0];
        const bf16* bufB = &lds[cur][1][0];
        bfrag af[4], bb[4];
#pragma unroll
        for (int mi = 0; mi < 4; mi++)
            af[mi] = *(const bfrag*)(bufA + (64 * wm + 16 * mi + c) * 32 + 8 * g);
#pragma unroll
        for (int ni = 0; ni < 4; ni++)
            bb[ni] = *(const bfrag*)(bufB + (64 * wn + 16 * ni + c) * 32 + 8 * g);
#pragma unroll
        for (int mi = 0; mi < 4; mi++)
#pragma unroll
            for (int ni = 0; ni < 4; ni++)
                acc[mi][ni] = __builtin_amdgcn_mfma_f32_16x16x32_bf16(
                    af[mi], bb[ni], acc[mi][ni], 0, 0, 0);
        __syncthreads();
    }

#pragma unroll
    for (int mi = 0; mi < 4; mi++)
#pragma unroll
        for (int ni = 0; ni < 4; ni++) {
            long row = m0 + 64 * wm + 16 * mi + 4 * g;
            long col = n0 + 64 * wn + 16 * ni + c;
#pragma unroll
            for (int r = 0; r < 4; r++)
                stf(&C[(row + r) * N + col], acc[mi][ni][r]);
        }
}

// ---------------------------------------------------------------------------
// RoPE + per-row L2 norm + sqk*sqrt(dm); QKVb bf16 layout [row][h*192+e].
// Emits bf16 Qb (sdpa scale folded), Kb, and Vt[h][b][d][T].
// ---------------------------------------------------------------------------
__global__ __launch_bounds__(256)
void rope_norm_qk(const bf16* __restrict__ QKVb, const float* __restrict__ sqk,
                  bf16* __restrict__ Qb, bf16* __restrict__ Kb, bf16* __restrict__ Vt)
{
    int gw   = (blockIdx.x * 256 + threadIdx.x) >> 6;   // 0 .. H*NROW-1
    int lane = threadIdx.x & 63;
    int h = gw / NROW, row = gw % NROW, t = row % T_, b = row / T_;

    const bf16* base = QKVb + (long)row * 3072 + h * 192;
    float q = __bfloat162float(base[lane]);
    float k = __bfloat162float(base[64 + lane]);
    bf16  v = base[128 + lane];

    int   j   = lane & 31;
    float inv = expf(-(float)j * (9.210340371976184f / 32.f));  // 10000^(-j/32)
    float ang = (float)t * inv;
    float s = sinf(ang), cc = cosf(ang);

    float qp = __shfl_xor(q, 32, 64);
    float kp = __shfl_xor(k, 32, 64);
    float sgn = (lane < 32) ? -1.f : 1.f;
    float qr = q * cc + sgn * qp * s;
    float kr = k * cc + sgn * kp * s;

    float qs = wave_sum(qr * qr);
    float ks = wave_sum(kr * kr);
    float se = sqk[h * 64 + lane] * 32.f;   // sqk * sqrt(dm)

    long idx = ((long)h * NROW + row) * 64 + lane;
    Qb[idx] = __float2bfloat16(qr * rsqrtf(qs) * se * 32.f);  // sdpa scale folded
    Kb[idx] = __float2bfloat16(kr * rsqrtf(ks) * se);
    Vt[((long)(h * B_ + b) * 64 + lane) * T_ + t] = v;
}

// ---------------------------------------------------------------------------
// MFMA flash attention, fixed-shift softmax, paired q-tiles, K/V staged in
// LDS per block (shared by 4 waves, double-buffered). Swizzle: 16B chunk
// index ^= (row&7) on the GLOBAL source; ds_read applies the same XOR.
// All 4 waves of a block have identical kt ranges (pr=blk*4+w => nA=blk,
// nB=31-blk for every w) -> zero barrier imbalance.
// ---------------------------------------------------------------------------
__global__ __launch_bounds__(256)
void attn_mfma(const bf16* __restrict__ Qb, const bf16* __restrict__ Kb,
               const bf16* __restrict__ Vt, bf16* __restrict__ O)
{
    __shared__ bf16 kv[2][2][64 * 64];    // [buf][K|V][row*64 + chunk-swizzled]

    int orig   = blockIdx.x;              // 0..1023
    int xcd    = orig & 7;
    int rest   = orig >> 3;               // 0..127
    int bh     = xcd * 8 + (rest & 7);    // 8 (b,h) per XCD -> 4MiB K/V in L2
    int blkraw = rest >> 3;               // 0..15
    int blk    = (blkraw & 1) ? (15 - (blkraw >> 1)) : (blkraw >> 1); // hvy/lt mix
    int w      = threadIdx.x >> 6;        // 0..3
    int pr     = blk * 4 + w;             // 0..63
    int h = bh >> 2, b = bh & 3;

    int lane = threadIdx.x & 63;
    int g = lane >> 4, c = lane & 15;

    const bf16* kbase = Kb + ((long)h * NROW + (long)b * T_) * 64;
    const bf16* vbase = Vt + (long)(h * B_ + b) * 64 * (long)T_;

    int q0A = pr * 16, q0B = (127 - pr) * 16;
    const bf16* qbA = Qb + ((long)h * NROW + (long)b * T_ + q0A) * 64;
    const bf16* qbB = Qb + ((long)h * NROW + (long)b * T_ + q0B) * 64;
    bfrag qfA0 = *(const bfrag*)(qbA + (long)c * 64 + 8 * g);
    bfrag qfA1 = *(const bfrag*)(qbA + (long)c * 64 + 32 + 8 * g);
    bfrag qfB0 = *(const bfrag*)(qbB + (long)c * 64 + 8 * g);
    bfrag qfB1 = *(const bfrag*)(qbB + (long)c * 64 + 32 + 8 * g);

    f4 otA[4] = {{0,0,0,0},{0,0,0,0},{0,0,0,0},{0,0,0,0}};
    f4 otB[4] = {{0,0,0,0},{0,0,0,0},{0,0,0,0},{0,0,0,0}};
    float lA = 0.f, lB = 0.f;

    const int nA = blk, nB = 31 - blk, KT = nB;
    int qgA = q0A + c, qgB = q0B + c;

    // staging constants: lane covers LDS row rb+ (lane>>3), 16B chunk lane&7;
    // source chunk pre-swizzled by row&7 = lane>>3.
    const int srow8  = lane >> 3;                 // 0..7
    const int schunk = (lane & 7) ^ srow8;        // swizzled source chunk
    const int swz    = 8 * schunk;                // element offset in row

    auto STAGE = [&](int buf, int kt) {
        int k0 = kt * 64;
#pragma unroll
        for (int i = 0; i < 2; i++) {
            int rb  = (w * 2 + i) * 8;            // row base 0..56
            int row = rb + srow8;
            gl_lds(kbase + (long)(k0 + row) * 64 + swz, &kv[buf][0][rb * 64]);
            gl_lds(vbase + (long)row * T_ + k0 + swz,   &kv[buf][1][rb * 64]);
        }
    };

    STAGE(0, 0);
    __syncthreads();

    const int cx = c & 7;

    for (int kt = 0; kt <= KT; kt++) {
        int buf = kt & 1;
        if (kt < KT) STAGE(buf ^ 1, kt + 1);

        const bf16* Kl = &kv[buf][0][0];
        const bf16* Vl = &kv[buf][1][0];
        int k0 = kt * 64;
        bool actA = (kt <= nA);
        unsigned wvA[8], wvB[8];

#pragma unroll
        for (int kb = 0; kb < 4; kb++) {
            const bf16* kr = Kl + (16 * kb + c) * 64;
            bfrag ka = *(const bfrag*)(kr + 8 * (g ^ cx));
            bfrag kc = *(const bfrag*)(kr + 8 * ((g | 4) ^ cx));

            f4 sB = {0, 0, 0, 0};
            sB = __builtin_amdgcn_mfma_f32_16x16x32_bf16(ka, qfB0, sB, 0, 0, 0);
            sB = __builtin_amdgcn_mfma_f32_16x16x32_bf16(kc, qfB1, sB, 0, 0, 0);
            if (kt == nB) {
#pragma unroll
                for (int r = 0; r < 4; r++)
                    if (k0 + 16 * kb + 4 * g + r > qgB) sB[r] = -1e30f;
            }
            float eB0 = __expf(sB[0] - 32.f), eB1 = __expf(sB[1] - 32.f);
            float eB2 = __expf(sB[2] - 32.f), eB3 = __expf(sB[3] - 32.f);
            lB += (eB0 + eB1) + (eB2 + eB3);
            wvB[2 * kb]     = pk2(eB0, eB1);
            wvB[2 * kb + 1] = pk2(eB2, eB3);

            if (actA) {
                f4 sA = {0, 0, 0, 0};
                sA = __builtin_amdgcn_mfma_f32_16x16x32_bf16(ka, qfA0, sA, 0, 0, 0);
                sA = __builtin_amdgcn_mfma_f32_16x16x32_bf16(kc, qfA1, sA, 0, 0, 0);
                if (kt == nA) {
#pragma unroll
                    for (int r = 0; r < 4; r++)
                        if (k0 + 16 * kb + 4 * g + r > qgA) sA[r] = -1e30f;
                }
                float eA0 = __expf(sA[0] - 32.f), eA1 = __expf(sA[1] - 32.f);
                float eA2 = __expf(sA[2] - 32.f), eA3 = __expf(sA[3] - 32.f);
                lA += (eA0 + eA1) + (eA2 + eA3);
                wvA[2 * kb]     = pk2(eA0, eA1);
                wvA[2 * kb + 1] = pk2(eA2, eA3);
            }
        }

        // PV: two 32-key halves; B-frag = P^T via lane exchange; V from LDS
#pragma unroll
        for (int p = 0; p < 2; p++) {
            int s0l = c + 32 * (g & 1), s1l = s0l + 16;
            bool hi = (g >= 2);

            unsigned Bb0 = (unsigned)__shfl((int)wvB[4 * p + 0], s0l, 64);
            unsigned Bb1 = (unsigned)__shfl((int)wvB[4 * p + 1], s0l, 64);
            unsigned Bb2 = (unsigned)__shfl((int)wvB[4 * p + 2], s0l, 64);
            unsigned Bb3 = (unsigned)__shfl((int)wvB[4 * p + 3], s0l, 64);
            unsigned Bb4 = (unsigned)__shfl((int)wvB[4 * p + 0], s1l, 64);
            unsigned Bb5 = (unsigned)__shfl((int)wvB[4 * p + 1], s1l, 64);
            unsigned Bb6 = (unsigned)__shfl((int)wvB[4 * p + 2], s1l, 64);
            unsigned Bb7 = (unsigned)__shfl((int)wvB[4 * p + 3], s1l, 64);
            union { bfrag f; unsigned u[4]; } pfB;
            pfB.u[0] = hi ? Bb2 : Bb0;
            pfB.u[1] = hi ? Bb3 : Bb1;
            pfB.u[2] = hi ? Bb6 : Bb4;
            pfB.u[3] = hi ? Bb7 : Bb5;

            union { bfrag f; unsigned u[4]; } pfA;
            if (actA) {
                unsigned Ab0 = (unsigned)__shfl((int)wvA[4 * p + 0], s0l, 64);
                unsigned Ab1 = (unsigned)__shfl((int)wvA[4 * p + 1], s0l, 64);
                unsigned Ab2 = (unsigned)__shfl((int)wvA[4 * p + 2], s0l, 64);
                unsigned Ab3 = (unsigned)__shfl((int)wvA[4 * p + 3], s0l, 64);
                unsigned Ab4 = (unsigned)__shfl((int)wvA[4 * p + 0], s1l, 64);
                unsigned Ab5 = (unsigned)__shfl((int)wvA[4 * p + 1], s1l, 64);
                unsigned Ab6 = (unsigned)__shfl((int)wvA[4 * p + 2], s1l, 64);
                unsigned Ab7 = (unsigned)__shfl((int)wvA[4 * p + 3], s1l, 64);
                pfA.u[0] = hi ? Ab2 : Ab0;
                pfA.u[1] = hi ? Ab3 : Ab1;
                pfA.u[2] = hi ? Ab6 : Ab4;
                pfA.u[3] = hi ? Ab7 : Ab5;
            }

#pragma unroll
            for (int dblk = 0; dblk < 4; dblk++) {
                bfrag vf = *(const bfrag*)(Vl + (16 * dblk + c) * 64
                                              + 8 * (((p << 2) | g) ^ cx));
                otB[dblk] = __builtin_amdgcn_mfma_f32_16x16x32_bf16(vf, pfB.f, otB[dblk], 0, 0, 0);
                if (actA)
                    otA[dblk] = __builtin_amdgcn_mfma_f32_16x16x32_bf16(vf, pfA.f, otA[dblk], 0, 0, 0);
            }
        }
        __syncthreads();
    }

    lA += __shfl_xor(lA, 16, 64); lA += __shfl_xor(lA, 32, 64);
    lB += __shfl_xor(lB, 16, 64); lB += __shfl_xor(lB, 32, 64);

    float invA = 1.f / lA, invB = 1.f / lB;
    long orowA = (long)(b * T_ + q0A + c) * DM + h * 64;
    long orowB = (long)(b * T_ + q0B + c) * DM + h * 64;
#pragma unroll
    for (int dblk = 0; dblk < 4; dblk++)
#pragma unroll
        for (int r = 0; r < 4; r++) {
            O[orowA + 16 * dblk + 4 * g + r] = __float2bfloat16(otA[dblk][r] * invA);
            O[orowB + 16 * dblk + 4 * g + r] = __float2bfloat16(otB[dblk][r] * invB);
        }
}

// ---------------------------------------------------------------------------
__global__ __launch_bounds__(256)
void lerp_norm(const float* __restrict__ X, const float* __restrict__ Tt,
               const float* __restrict__ alpha, float ascale,
               float* __restrict__ Out, bf16* __restrict__ OutB)
{
    long row = blockIdx.x;
    const float* xr = X  + row * DM;
    const float* tr = Tt + row * DM;
    int tid = threadIdx.x;

    float xs[4], ts[4], sx = 0.f, st = 0.f;
#pragma unroll
    for (int i = 0; i < 4; i++) {
        int d = tid + 256 * i;
        xs[i] = xr[d]; ts[i] = tr[d];
        sx += xs[i] * xs[i]; st += ts[i] * ts[i];
    }
    sx = block_sum(sx);
    st = block_sum(st);
    float ix = rsqrtf(sx), it = rsqrtf(st);

    float ys[4], sy = 0.f;
#pragma unroll
    for (int i = 0; i < 4; i++) {
        int d = tid + 256 * i;
        float a  = xs[i] * ix;
        float bn = ts[i] * it;
        float lr = fabsf(alpha[d] * ascale);
        ys[i] = a + lr * (bn - a);
        sy += ys[i] * ys[i];
    }
    sy = block_sum(sy);
    float iy = rsqrtf(sy);
#pragma unroll
    for (int i = 0; i < 4; i++) {
        int d = tid + 256 * i;
        float o = ys[i] * iy;
        Out[row * DM + d] = o;
        if (OutB) OutB[row * DM + d] = __float2bfloat16(o);
    }
}

// ---------------------------------------------------------------------------
__global__ __launch_bounds__(256)
void mlp_act(const bf16* __restrict__ UV, const float* __restrict__ suv,
             bf16* __restrict__ R)
{
    long row = blockIdx.x;
    const bf16* ur = UV + row * 8192;
    int tid = threadIdx.x;

    float ss = 0.f;
#pragma unroll
    for (int i = 0; i < 32; i++) {
        int j = tid + 256 * i;
        float v = __bfloat162float(ur[j]) * suv[j] * 32.f;
        ss += v * v;
    }
    ss = block_sum(ss);
    float inv = rsqrtf(ss);

#pragma unroll
    for (int i = 0; i < 16; i++) {
        int j = tid + 256 * i;
        float u = __bfloat162float(ur[j])        * suv[j]        * 32.f * inv;
        float v = __bfloat162float(ur[4096 + j]) * suv[4096 + j] * 32.f * inv;
        float sil = v / (1.f + __expf(-v));
        R[row * 4096 + j] = __float2bfloat16(u * sil);
    }
}

// ---------------------------------------------------------------------------
extern "C" void kernel_launch(void* const* d_in, const int* in_sizes, int n_in,
                              void* d_out, int out_size, void* d_ws, size_t ws_size,
                              hipStream_t stream)
{
    const float* x          = (const float*)d_in[0];
    const float* qkv_w      = (const float*)d_in[1];
    const float* sqk        = (const float*)d_in[2];
    const float* W_O        = (const float*)d_in[3];
    const float* Wu         = (const float*)d_in[4];
    const float* Wv         = (const float*)d_in[5];
    const float* attn_alpha = (const float*)d_in[6];
    const float* mlp_alpha  = (const float*)d_in[7];
    const float* suv        = (const float*)d_in[8];
    float* out = (float*)d_out;

    const long MiB = 1048576;
    char* ws = (char*)d_ws;
    float* x1    = (float*)(ws + 0 * MiB);
    bf16*  x1b   = (bf16*) (ws + 32 * MiB);
    bf16*  QKVb  = (bf16*) (ws + 48 * MiB);
    float* tbuf  = (float*)(ws + 48 * MiB);
    bf16*  uv    = (bf16*) (ws + 48 * MiB);   // half: [4096][8192]
    float* t2    = (float*)(ws + 48 * MiB);
    bf16*  xb    = (bf16*) (ws + 144 * MiB);
    bf16*  Qb    = (bf16*) (ws + 144 * MiB);
    bf16*  Wub   = (bf16*) (ws + 144 * MiB);
    bf16*  Kb    = (bf16*) (ws + 160 * MiB);
    bf16*  Vt    = (bf16*) (ws + 176 * MiB);
    bf16*  Wvb   = (bf16*) (ws + 176 * MiB);
    bf16*  res   = (bf16*) (ws + 112 * MiB);  // [8192][4096]
    bf16*  qkvwb = (bf16*) (ws + 192 * MiB);
    bf16*  attno = (bf16*) (ws + 192 * MiB);
    bf16*  Wob   = (bf16*) (ws + 208 * MiB);
    // peak 210 MiB

    // 0) converts needed before attn
    f32_to_bf16_k<<<4096, 256, 0, stream>>>(x, xb, 8388608L);
    f32_to_bf16_k<<<1536, 256, 0, stream>>>(qkv_w, qkvwb, 3145728L);
    f32_to_bf16_k<<<512,  256, 0, stream>>>(W_O, Wob, 1048576L);

    // 1) QKV projection -> bf16 [8192][3072]
    gemm_bf16<bf16><<<dim3(24, 64), 256, 0, stream>>>(xb, qkvwb, QKVb, NROW, 3072, DM);

    // 2) RoPE + justnorm + scaling -> Qb/Kb/Vt
    rope_norm_qk<<<(H_ * NROW) / 4, 256, 0, stream>>>(QKVb, sqk, Qb, Kb, Vt);

    // 3) MFMA flash attention -> attno bf16 (overwrites qkvwb region)
    attn_mfma<<<1024, 256, 0, stream>>>(Qb, Kb, Vt, attno);

    // 4) W_O projection -> tbuf fp32 (QKVb region dead)
    gemm_bf16<float><<<dim3(8, 64), 256, 0, stream>>>(attno, Wob, tbuf, NROW, DM, DM);

    // 5) attention residual lerp-norm -> x1 fp32 + x1b bf16
    lerp_norm<<<NROW, 256, 0, stream>>>(x, tbuf, attn_alpha, 1.6f, x1, x1b);

    // 6) weight converts for MLP (Qb/Kb/Vt dead)
    f32_to_bf16_k<<<4096, 256, 0, stream>>>(Wu, Wub, 8388608L);
    f32_to_bf16_k<<<2048, 256, 0, stream>>>(Wv, Wvb, 4194304L);

    // 7) MLP in two M-halves: uv(half) = x1b @ Wu^T -> bf16; act -> res
    for (int half = 0; half < 2; half++) {
        gemm_bf16<bf16><<<dim3(64, 32), 256, 0, stream>>>(
            x1b + (long)half * 4096 * DM, Wub, uv, 4096, 8 * DM, DM);
        mlp_act<<<4096, 256, 0, stream>>>(uv, suv, res + (long)half * 4096 * 4096);
    }
    // note: mlp_act(half2) clobbers Wub region — Wub dead by then.

    // 8) t2 = res @ Wv^T -> fp32 (uv dead)
    gemm_bf16<float><<<dim3(8, 64), 256, 0, stream>>>(res, Wvb, t2, NROW, DM, 4 * DM);

    // 9) MLP residual lerp-norm -> out
    lerp_norm<<<NROW, 256, 0, stream>>>(x1, t2, mlp_alpha, 0.05f, out, (bf16*)nullptr);
}

// Round 8
// 588.922 us; speedup vs baseline: 22.0889x; 1.0401x over previous
//
#include <hip/hip_runtime.h>
#include <hip/hip_bf16.h>

// nGPT-style transformer layer, MI355X. Round 7: 256^2 8-wave deep-pipelined
// GEMM (counted vmcnt, T2 swizzle, T5 setprio) for QKV and Wu. Attention and
// the rest unchanged from round 6.
// B=4 T=2048 dm=1024 H=16 di=64.
//
// Workspace arena (peak 210 MiB). Aliasing is ORDER-SENSITIVE; launch order in
// kernel_launch is the contract (same as rounds 5-6).

#define B_   4
#define T_   2048
#define DM   1024
#define H_   16
#define DI   64
#define NROW (B_ * T_)   // 8192

using bf16 = __hip_bfloat16;
typedef __attribute__((ext_vector_type(8))) short bfrag;   // 8 bf16 (4 VGPR)
typedef __attribute__((ext_vector_type(4))) float f4;

__device__ __forceinline__ void  stf(float* p, float v) { *p = v; }
__device__ __forceinline__ void  stf(bf16* p, float v)  { *p = __float2bfloat16(v); }

__device__ __forceinline__ unsigned short bfbits(float a) {
    bf16 h = __float2bfloat16(a);
    return __builtin_bit_cast(unsigned short, h);
}
__device__ __forceinline__ unsigned pk2(float a, float b) {
    return (unsigned)bfbits(a) | ((unsigned)bfbits(b) << 16);
}

__device__ __forceinline__ float wave_sum(float v) {
#pragma unroll
    for (int off = 32; off; off >>= 1) v += __shfl_xor(v, off, 64);
    return v;
}

__device__ __forceinline__ float block_sum(float v) {
    __shared__ float sm[4];
    int lane = threadIdx.x & 63, w = threadIdx.x >> 6;
    v = wave_sum(v);
    __syncthreads();
    if (lane == 0) sm[w] = v;
    __syncthreads();
    return sm[0] + sm[1] + sm[2] + sm[3];
}

// async global->LDS, 16B per lane; LDS dest = wave-uniform base + lane*16
typedef __attribute__((address_space(1))) const void g_void;
typedef __attribute__((address_space(3))) void l_void;
__device__ __forceinline__ void gl_lds(const void* g, void* l) {
    __builtin_amdgcn_global_load_lds((g_void*)g, (l_void*)l, 16, 0, 0);
}

// ---------------------------------------------------------------------------
// f32 -> bf16 convert, 8 elems/thread. n must be a multiple of 2048.
// ---------------------------------------------------------------------------
__global__ __launch_bounds__(256)
void f32_to_bf16_k(const float* __restrict__ in, bf16* __restrict__ out, long n)
{
    long i = ((long)blockIdx.x * 256 + threadIdx.x) * 8;
    if (i >= n) return;
    float4 a = *(const float4*)(in + i);
    float4 b = *(const float4*)(in + i + 4);
    union { bfrag f; unsigned u[4]; } o;
    o.u[0] = pk2(a.x, a.y); o.u[1] = pk2(a.z, a.w);
    o.u[2] = pk2(b.x, b.y); o.u[3] = pk2(b.z, b.w);
    *(bfrag*)(out + i) = o.f;
}

// ---------------------------------------------------------------------------
// C = A * B^T, 128x128 tile, BK=32, 4 waves, m97 structure (kept for the
// N=1024 GEMMs where a 256-wide tile would leave half the grid idle).
// ---------------------------------------------------------------------------
template <typename TC>
__global__ __launch_bounds__(256)
void gemm_bf16(const bf16* __restrict__ A, const bf16* __restrict__ Bm,
               TC* __restrict__ C, int M, int N, int K)
{
    __shared__ bf16 lds[2][2][128 * 32];   // [buf][A|B][row*32+k]
    const int tid  = threadIdx.x;
    const int w    = tid >> 6, lane = tid & 63;
    const int g    = lane >> 4, c = lane & 15;
    const int m0   = blockIdx.y * 128, n0 = blockIdx.x * 128;
    const int wm   = w >> 1, wn = w & 1;

    const int srow = (lane >> 2);        // 0..15 within chunk
    const int skc  = 8 * (lane & 3);     // k elem offset 0,8,16,24

    f4 acc[4][4] = {{{0,0,0,0}}};

    const int NT = K >> 5;               // K/32 steps

#pragma unroll
    for (int q = 0; q < 2; q++) {
        int cidx = w * 2 + q;            // 0..7, covers rows [16*cidx,+16)
        int row  = 16 * cidx + srow;
        gl_lds(A + (long)(m0 + row) * K + skc, &lds[0][0][cidx * 512]);
        gl_lds(Bm + (long)(n0 + row) * K + skc, &lds[0][1][cidx * 512]);
    }
    __syncthreads();

    for (int t = 0; t < NT; t++) {
        int cur = t & 1;
        if (t + 1 < NT) {
            int k0 = (t + 1) << 5;
#pragma unroll
            for (int q = 0; q < 2; q++) {
                int cidx = w * 2 + q;
                int row  = 16 * cidx + srow;
                gl_lds(A + (long)(m0 + row) * K + k0 + skc, &lds[cur ^ 1][0][cidx * 512]);
                gl_lds(Bm + (long)(n0 + row) * K + k0 + skc, &lds[cur ^ 1][1][cidx * 512]);
            }
        }
        const bf16* bufA = &lds[cur][0][0];
        const bf16* bufB = &lds[cur][1][0];
        bfrag af[4], bb[4];
#pragma unroll
        for (int mi = 0; mi < 4; mi++)
            af[mi] = *(const bfrag*)(bufA + (64 * wm + 16 * mi + c) * 32 + 8 * g);
#pragma unroll
        for (int ni = 0; ni < 4; ni++)
            bb[ni] = *(const bfrag*)(bufB + (64 * wn + 16 * ni + c) * 32 + 8 * g);
#pragma unroll
        for (int mi = 0; mi < 4; mi++)
#pragma unroll
            for (int ni = 0; ni < 4; ni++)
                acc[mi][ni] = __builtin_amdgcn_mfma_f32_16x16x32_bf16(
                    af[mi], bb[ni], acc[mi][ni], 0, 0, 0);
        __syncthreads();
    }

#pragma unroll
    for (int mi = 0; mi < 4; mi++)
#pragma unroll
        for (int ni = 0; ni < 4; ni++) {
            long row = m0 + 64 * wm + 16 * mi + 4 * g;
            long col = n0 + 64 * wn + 16 * ni + c;
#pragma unroll
            for (int r = 0; r < 4; r++)
                stf(&C[(row + r) * N + col], acc[mi][ni][r]);
        }
}

// ---------------------------------------------------------------------------
// C = A * B^T, 256x256 tile, BK=64, 8 waves (2M x 4N), 128KB LDS dbuf.
// Deep pipeline: 2 tiles prefetched via global_load_lds; counted
// s_waitcnt vmcnt(8) (never 0 in steady state); raw s_barrier pairs;
// (row&7) chunk-XOR swizzle on BOTH sides (pre-swizzled global source,
// swizzled ds_read) -> 2-way bank aliasing (free). setprio around MFMA.
// Requires M,N %256==0, K %64==0, K>=128.
// Sync contract per iteration t:
//   compute buf[t&1] (all ds_reads lgkm-drained before MFMAs)
//   s_barrier                      -- nobody reads buf[t&1] anymore
//   STAGE tile t+2 -> buf[t&1]; s_waitcnt vmcnt(8)  -- tile t+1 landed
//   s_barrier                      -- tile t+1 visible to all waves
// ---------------------------------------------------------------------------
template <typename TC>
__global__ __launch_bounds__(512, 2)
void gemm_bf16_256(const bf16* __restrict__ A, const bf16* __restrict__ Bm,
                   TC* __restrict__ C, int M, int N, int K)
{
    __shared__ bf16 lds[2][2][256 * 64];   // 128 KiB
    const int tid  = threadIdx.x;
    const int w    = tid >> 6, lane = tid & 63;
    const int g    = lane >> 4, c = lane & 15;
    const int m0   = blockIdx.y * 256, n0 = blockIdx.x * 256;
    const int wm   = w & 1, wn = w >> 1;          // 2M x 4N wave grid
    const int srow8 = lane >> 3;                  // 0..7
    const int swz   = 8 * ((lane & 7) ^ srow8);   // pre-swizzled source chunk
    const int cx    = c & 7;

    f4 acc[8][4] = {{{0,0,0,0}}};

    const int NT = K >> 6;

    auto STAGE = [&](int buf, int t) {
        int k0 = t << 6;
#pragma unroll
        for (int i = 0; i < 4; i++) {
            int rb = w * 32 + i * 8;              // 8 rows per gl_lds
            gl_lds(A  + (long)(m0 + rb + srow8) * K + k0 + swz, &lds[buf][0][rb * 64]);
            gl_lds(Bm + (long)(n0 + rb + srow8) * K + k0 + swz, &lds[buf][1][rb * 64]);
        }
    };

    // prologue: tiles 0 and 1 issued; wait tile 0 (8 newest still in flight)
    STAGE(0, 0);
    STAGE(1, 1);
    asm volatile("s_waitcnt vmcnt(8)" ::: "memory");
    __builtin_amdgcn_s_barrier();

    for (int t = 0; t < NT; t++) {
        const bf16* bufA = &lds[t & 1][0][0];
        const bf16* bufB = &lds[t & 1][1][0];

        bfrag a0[4][2], b0[4][2];
#pragma unroll
        for (int mi = 0; mi < 4; mi++)
#pragma unroll
            for (int kk = 0; kk < 2; kk++)
                a0[mi][kk] = *(const bfrag*)(bufA + (wm * 128 + mi * 16 + c) * 64
                                                  + 8 * ((4 * kk + g) ^ cx));
#pragma unroll
        for (int ni = 0; ni < 4; ni++)
#pragma unroll
            for (int kk = 0; kk < 2; kk++)
                b0[ni][kk] = *(const bfrag*)(bufB + (wn * 64 + ni * 16 + c) * 64
                                                  + 8 * ((4 * kk + g) ^ cx));
        asm volatile("s_waitcnt lgkmcnt(0)" ::: "memory");
        __builtin_amdgcn_sched_barrier(0);
        __builtin_amdgcn_s_setprio(1);
#pragma unroll
        for (int mi = 0; mi < 4; mi++)
#pragma unroll
            for (int ni = 0; ni < 4; ni++) {
                acc[mi][ni] = __builtin_amdgcn_mfma_f32_16x16x32_bf16(
                    a0[mi][0], b0[ni][0], acc[mi][ni], 0, 0, 0);
                acc[mi][ni] = __builtin_amdgcn_mfma_f32_16x16x32_bf16(
                    a0[mi][1], b0[ni][1], acc[mi][ni], 0, 0, 0);
            }
        __builtin_amdgcn_s_setprio(0);

        bfrag a1[4][2];
#pragma unroll
        for (int mi = 0; mi < 4; mi++)
#pragma unroll
            for (int kk = 0; kk < 2; kk++)
                a1[mi][kk] = *(const bfrag*)(bufA + (wm * 128 + (mi + 4) * 16 + c) * 64
                                                  + 8 * ((4 * kk + g) ^ cx));
        asm volatile("s_waitcnt lgkmcnt(0)" ::: "memory");
        __builtin_amdgcn_sched_barrier(0);
        __builtin_amdgcn_s_setprio(1);
#pragma unroll
        for (int mi = 0; mi < 4; mi++)
#pragma unroll
            for (int ni = 0; ni < 4; ni++) {
                acc[mi + 4][ni] = __builtin_amdgcn_mfma_f32_16x16x32_bf16(
                    a1[mi][0], b0[ni][0], acc[mi + 4][ni], 0, 0, 0);
                acc[mi + 4][ni] = __builtin_amdgcn_mfma_f32_16x16x32_bf16(
                    a1[mi][1], b0[ni][1], acc[mi + 4][ni], 0, 0, 0);
            }
        __builtin_amdgcn_s_setprio(0);

        __builtin_amdgcn_s_barrier();
        if (t + 2 < NT) {
            STAGE(t & 1, t + 2);
            asm volatile("s_waitcnt vmcnt(8)" ::: "memory");
        } else if (t + 1 < NT) {
            asm volatile("s_waitcnt vmcnt(0)" ::: "memory");
        }
        __builtin_amdgcn_s_barrier();
    }

#pragma unroll
    for (int mi = 0; mi < 8; mi++)
#pragma unroll
        for (int ni = 0; ni < 4; ni++) {
            long row = m0 + wm * 128 + mi * 16 + 4 * g;
            long col = n0 + wn * 64 + ni * 16 + c;
#pragma unroll
            for (int r = 0; r < 4; r++)
                stf(&C[(row + r) * N + col], acc[mi][ni][r]);
        }
}

// ---------------------------------------------------------------------------
// RoPE + per-row L2 norm + sqk*sqrt(dm); QKVb bf16 layout [row][h*192+e].
// Emits bf16 Qb (sdpa scale folded), Kb, and Vt[h][b][d][T].
// ---------------------------------------------------------------------------
__global__ __launch_bounds__(256)
void rope_norm_qk(const bf16* __restrict__ QKVb, const float* __restrict__ sqk,
                  bf16* __restrict__ Qb, bf16* __restrict__ Kb, bf16* __restrict__ Vt)
{
    int gw   = (blockIdx.x * 256 + threadIdx.x) >> 6;   // 0 .. H*NROW-1
    int lane = threadIdx.x & 63;
    int h = gw / NROW, row = gw % NROW, t = row % T_, b = row / T_;

    const bf16* base = QKVb + (long)row * 3072 + h * 192;
    float q = __bfloat162float(base[lane]);
    float k = __bfloat162float(base[64 + lane]);
    bf16  v = base[128 + lane];

    int   j   = lane & 31;
    float inv = expf(-(float)j * (9.210340371976184f / 32.f));  // 10000^(-j/32)
    float ang = (float)t * inv;
    float s = sinf(ang), cc = cosf(ang);

    float qp = __shfl_xor(q, 32, 64);
    float kp = __shfl_xor(k, 32, 64);
    float sgn = (lane < 32) ? -1.f : 1.f;
    float qr = q * cc + sgn * qp * s;
    float kr = k * cc + sgn * kp * s;

    float qs = wave_sum(qr * qr);
    float ks = wave_sum(kr * kr);
    float se = sqk[h * 64 + lane] * 32.f;   // sqk * sqrt(dm)

    long idx = ((long)h * NROW + row) * 64 + lane;
    Qb[idx] = __float2bfloat16(qr * rsqrtf(qs) * se * 32.f);  // sdpa scale folded
    Kb[idx] = __float2bfloat16(kr * rsqrtf(ks) * se);
    Vt[((long)(h * B_ + b) * 64 + lane) * T_ + t] = v;
}

// ---------------------------------------------------------------------------
// MFMA flash attention, fixed-shift softmax, paired q-tiles, K/V staged in
// LDS per block (shared by 4 waves, double-buffered, chunk-XOR swizzled).
// ---------------------------------------------------------------------------
__global__ __launch_bounds__(256)
void attn_mfma(const bf16* __restrict__ Qb, const bf16* __restrict__ Kb,
               const bf16* __restrict__ Vt, bf16* __restrict__ O)
{
    __shared__ bf16 kv[2][2][64 * 64];    // [buf][K|V][row*64 + chunk-swizzled]

    int orig   = blockIdx.x;              // 0..1023
    int xcd    = orig & 7;
    int rest   = orig >> 3;               // 0..127
    int bh     = xcd * 8 + (rest & 7);    // 8 (b,h) per XCD -> 4MiB K/V in L2
    int blkraw = rest >> 3;               // 0..15
    int blk    = (blkraw & 1) ? (15 - (blkraw >> 1)) : (blkraw >> 1); // hvy/lt mix
    int w      = threadIdx.x >> 6;        // 0..3
    int pr     = blk * 4 + w;             // 0..63
    int h = bh >> 2, b = bh & 3;

    int lane = threadIdx.x & 63;
    int g = lane >> 4, c = lane & 15;

    const bf16* kbase = Kb + ((long)h * NROW + (long)b * T_) * 64;
    const bf16* vbase = Vt + (long)(h * B_ + b) * 64 * (long)T_;

    int q0A = pr * 16, q0B = (127 - pr) * 16;
    const bf16* qbA = Qb + ((long)h * NROW + (long)b * T_ + q0A) * 64;
    const bf16* qbB = Qb + ((long)h * NROW + (long)b * T_ + q0B) * 64;
    bfrag qfA0 = *(const bfrag*)(qbA + (long)c * 64 + 8 * g);
    bfrag qfA1 = *(const bfrag*)(qbA + (long)c * 64 + 32 + 8 * g);
    bfrag qfB0 = *(const bfrag*)(qbB + (long)c * 64 + 8 * g);
    bfrag qfB1 = *(const bfrag*)(qbB + (long)c * 64 + 32 + 8 * g);

    f4 otA[4] = {{0,0,0,0},{0,0,0,0},{0,0,0,0},{0,0,0,0}};
    f4 otB[4] = {{0,0,0,0},{0,0,0,0},{0,0,0,0},{0,0,0,0}};
    float lA = 0.f, lB = 0.f;

    const int nA = blk, nB = 31 - blk, KT = nB;
    int qgA = q0A + c, qgB = q0B + c;

    const int srow8  = lane >> 3;                 // 0..7
    const int schunk = (lane & 7) ^ srow8;        // swizzled source chunk
    const int swz    = 8 * schunk;                // element offset in row

    auto STAGE = [&](int buf, int kt) {
        int k0 = kt * 64;
#pragma unroll
        for (int i = 0; i < 2; i++) {
            int rb  = (w * 2 + i) * 8;            // row base 0..56
            int row = rb + srow8;
            gl_lds(kbase + (long)(k0 + row) * 64 + swz, &kv[buf][0][rb * 64]);
            gl_lds(vbase + (long)row * T_ + k0 + swz,   &kv[buf][1][rb * 64]);
        }
    };

    STAGE(0, 0);
    __syncthreads();

    const int cx = c & 7;

    for (int kt = 0; kt <= KT; kt++) {
        int buf = kt & 1;
        if (kt < KT) STAGE(buf ^ 1, kt + 1);

        const bf16* Kl = &kv[buf][0][0];
        const bf16* Vl = &kv[buf][1][0];
        int k0 = kt * 64;
        bool actA = (kt <= nA);
        unsigned wvA[8], wvB[8];

#pragma unroll
        for (int kb = 0; kb < 4; kb++) {
            const bf16* kr = Kl + (16 * kb + c) * 64;
            bfrag ka = *(const bfrag*)(kr + 8 * (g ^ cx));
            bfrag kc = *(const bfrag*)(kr + 8 * ((g | 4) ^ cx));

            f4 sB = {0, 0, 0, 0};
            sB = __builtin_amdgcn_mfma_f32_16x16x32_bf16(ka, qfB0, sB, 0, 0, 0);
            sB = __builtin_amdgcn_mfma_f32_16x16x32_bf16(kc, qfB1, sB, 0, 0, 0);
            if (kt == nB) {
#pragma unroll
                for (int r = 0; r < 4; r++)
                    if (k0 + 16 * kb + 4 * g + r > qgB) sB[r] = -1e30f;
            }
            float eB0 = __expf(sB[0] - 32.f), eB1 = __expf(sB[1] - 32.f);
            float eB2 = __expf(sB[2] - 32.f), eB3 = __expf(sB[3] - 32.f);
            lB += (eB0 + eB1) + (eB2 + eB3);
            wvB[2 * kb]     = pk2(eB0, eB1);
            wvB[2 * kb + 1] = pk2(eB2, eB3);

            if (actA) {
                f4 sA = {0, 0, 0, 0};
                sA = __builtin_amdgcn_mfma_f32_16x16x32_bf16(ka, qfA0, sA, 0, 0, 0);
                sA = __builtin_amdgcn_mfma_f32_16x16x32_bf16(kc, qfA1, sA, 0, 0, 0);
                if (kt == nA) {
#pragma unroll
                    for (int r = 0; r < 4; r++)
                        if (k0 + 16 * kb + 4 * g + r > qgA) sA[r] = -1e30f;
                }
                float eA0 = __expf(sA[0] - 32.f), eA1 = __expf(sA[1] - 32.f);
                float eA2 = __expf(sA[2] - 32.f), eA3 = __expf(sA[3] - 32.f);
                lA += (eA0 + eA1) + (eA2 + eA3);
                wvA[2 * kb]     = pk2(eA0, eA1);
                wvA[2 * kb + 1] = pk2(eA2, eA3);
            }
        }

        // PV: two 32-key halves; B-frag = P^T via lane exchange; V from LDS
#pragma unroll
        for (int p = 0; p < 2; p++) {
            int s0l = c + 32 * (g & 1), s1l = s0l + 16;
            bool hi = (g >= 2);

            unsigned Bb0 = (unsigned)__shfl((int)wvB[4 * p + 0], s0l, 64);
            unsigned Bb1 = (unsigned)__shfl((int)wvB[4 * p + 1], s0l, 64);
            unsigned Bb2 = (unsigned)__shfl((int)wvB[4 * p + 2], s0l, 64);
            unsigned Bb3 = (unsigned)__shfl((int)wvB[4 * p + 3], s0l, 64);
            unsigned Bb4 = (unsigned)__shfl((int)wvB[4 * p + 0], s1l, 64);
            unsigned Bb5 = (unsigned)__shfl((int)wvB[4 * p + 1], s1l, 64);
            unsigned Bb6 = (unsigned)__shfl((int)wvB[4 * p + 2], s1l, 64);
            unsigned Bb7 = (unsigned)__shfl((int)wvB[4 * p + 3], s1l, 64);
            union { bfrag f; unsigned u[4]; } pfB;
            pfB.u[0] = hi ? Bb2 : Bb0;
            pfB.u[1] = hi ? Bb3 : Bb1;
            pfB.u[2] = hi ? Bb6 : Bb4;
            pfB.u[3] = hi ? Bb7 : Bb5;

            union { bfrag f; unsigned u[4]; } pfA;
            if (actA) {
                unsigned Ab0 = (unsigned)__shfl((int)wvA[4 * p + 0], s0l, 64);
                unsigned Ab1 = (unsigned)__shfl((int)wvA[4 * p + 1], s0l, 64);
                unsigned Ab2 = (unsigned)__shfl((int)wvA[4 * p + 2], s0l, 64);
                unsigned Ab3 = (unsigned)__shfl((int)wvA[4 * p + 3], s0l, 64);
                unsigned Ab4 = (unsigned)__shfl((int)wvA[4 * p + 0], s1l, 64);
                unsigned Ab5 = (unsigned)__shfl((int)wvA[4 * p + 1], s1l, 64);
                unsigned Ab6 = (unsigned)__shfl((int)wvA[4 * p + 2], s1l, 64);
                unsigned Ab7 = (unsigned)__shfl((int)wvA[4 * p + 3], s1l, 64);
                pfA.u[0] = hi ? Ab2 : Ab0;
                pfA.u[1] = hi ? Ab3 : Ab1;
                pfA.u[2] = hi ? Ab6 : Ab4;
                pfA.u[3] = hi ? Ab7 : Ab5;
            }

#pragma unroll
            for (int dblk = 0; dblk < 4; dblk++) {
                bfrag vf = *(const bfrag*)(Vl + (16 * dblk + c) * 64
                                              + 8 * (((p << 2) | g) ^ cx));
                otB[dblk] = __builtin_amdgcn_mfma_f32_16x16x32_bf16(vf, pfB.f, otB[dblk], 0, 0, 0);
                if (actA)
                    otA[dblk] = __builtin_amdgcn_mfma_f32_16x16x32_bf16(vf, pfA.f, otA[dblk], 0, 0, 0);
            }
        }
        __syncthreads();
    }

    lA += __shfl_xor(lA, 16, 64); lA += __shfl_xor(lA, 32, 64);
    lB += __shfl_xor(lB, 16, 64); lB += __shfl_xor(lB, 32, 64);

    float invA = 1.f / lA, invB = 1.f / lB;
    long orowA = (long)(b * T_ + q0A + c) * DM + h * 64;
    long orowB = (long)(b * T_ + q0B + c) * DM + h * 64;
#pragma unroll
    for (int dblk = 0; dblk < 4; dblk++)
#pragma unroll
        for (int r = 0; r < 4; r++) {
            O[orowA + 16 * dblk + 4 * g + r] = __float2bfloat16(otA[dblk][r] * invA);
            O[orowB + 16 * dblk + 4 * g + r] = __float2bfloat16(otB[dblk][r] * invB);
        }
}

// ---------------------------------------------------------------------------
__global__ __launch_bounds__(256)
void lerp_norm(const float* __restrict__ X, const float* __restrict__ Tt,
               const float* __restrict__ alpha, float ascale,
               float* __restrict__ Out, bf16* __restrict__ OutB)
{
    long row = blockIdx.x;
    const float* xr = X  + row * DM;
    const float* tr = Tt + row * DM;
    int tid = threadIdx.x;

    float xs[4], ts[4], sx = 0.f, st = 0.f;
#pragma unroll
    for (int i = 0; i < 4; i++) {
        int d = tid + 256 * i;
        xs[i] = xr[d]; ts[i] = tr[d];
        sx += xs[i] * xs[i]; st += ts[i] * ts[i];
    }
    sx = block_sum(sx);
    st = block_sum(st);
    float ix = rsqrtf(sx), it = rsqrtf(st);

    float ys[4], sy = 0.f;
#pragma unroll
    for (int i = 0; i < 4; i++) {
        int d = tid + 256 * i;
        float a  = xs[i] * ix;
        float bn = ts[i] * it;
        float lr = fabsf(alpha[d] * ascale);
        ys[i] = a + lr * (bn - a);
        sy += ys[i] * ys[i];
    }
    sy = block_sum(sy);
    float iy = rsqrtf(sy);
#pragma unroll
    for (int i = 0; i < 4; i++) {
        int d = tid + 256 * i;
        float o = ys[i] * iy;
        Out[row * DM + d] = o;
        if (OutB) OutB[row * DM + d] = __float2bfloat16(o);
    }
}

// ---------------------------------------------------------------------------
__global__ __launch_bounds__(256)
void mlp_act(const bf16* __restrict__ UV, const float* __restrict__ suv,
             bf16* __restrict__ R)
{
    long row = blockIdx.x;
    const bf16* ur = UV + row * 8192;
    int tid = threadIdx.x;

    float ss = 0.f;
#pragma unroll
    for (int i = 0; i < 32; i++) {
        int j = tid + 256 * i;
        float v = __bfloat162float(ur[j]) * suv[j] * 32.f;
        ss += v * v;
    }
    ss = block_sum(ss);
    float inv = rsqrtf(ss);

#pragma unroll
    for (int i = 0; i < 16; i++) {
        int j = tid + 256 * i;
        float u = __bfloat162float(ur[j])        * suv[j]        * 32.f * inv;
        float v = __bfloat162float(ur[4096 + j]) * suv[4096 + j] * 32.f * inv;
        float sil = v / (1.f + __expf(-v));
        R[row * 4096 + j] = __float2bfloat16(u * sil);
    }
}

// ---------------------------------------------------------------------------
extern "C" void kernel_launch(void* const* d_in, const int* in_sizes, int n_in,
                              void* d_out, int out_size, void* d_ws, size_t ws_size,
                              hipStream_t stream)
{
    const float* x          = (const float*)d_in[0];
    const float* qkv_w      = (const float*)d_in[1];
    const float* sqk        = (const float*)d_in[2];
    const float* W_O        = (const float*)d_in[3];
    const float* Wu         = (const float*)d_in[4];
    const float* Wv         = (const float*)d_in[5];
    const float* attn_alpha = (const float*)d_in[6];
    const float* mlp_alpha  = (const float*)d_in[7];
    const float* suv        = (const float*)d_in[8];
    float* out = (float*)d_out;

    const long MiB = 1048576;
    char* ws = (char*)d_ws;
    float* x1    = (float*)(ws + 0 * MiB);
    bf16*  x1b   = (bf16*) (ws + 32 * MiB);
    bf16*  QKVb  = (bf16*) (ws + 48 * MiB);
    float* tbuf  = (float*)(ws + 48 * MiB);
    bf16*  uv    = (bf16*) (ws + 48 * MiB);   // half: [4096][8192]
    float* t2    = (float*)(ws + 48 * MiB);
    bf16*  xb    = (bf16*) (ws + 144 * MiB);
    bf16*  Qb    = (bf16*) (ws + 144 * MiB);
    bf16*  Wub   = (bf16*) (ws + 144 * MiB);
    bf16*  Kb    = (bf16*) (ws + 160 * MiB);
    bf16*  Vt    = (bf16*) (ws + 176 * MiB);
    bf16*  Wvb   = (bf16*) (ws + 176 * MiB);
    bf16*  res   = (bf16*) (ws + 112 * MiB);  // [8192][4096]
    bf16*  qkvwb = (bf16*) (ws + 192 * MiB);
    bf16*  attno = (bf16*) (ws + 192 * MiB);
    bf16*  Wob   = (bf16*) (ws + 208 * MiB);
    // peak 210 MiB

    // 0) converts needed before attn
    f32_to_bf16_k<<<4096, 256, 0, stream>>>(x, xb, 8388608L);
    f32_to_bf16_k<<<1536, 256, 0, stream>>>(qkv_w, qkvwb, 3145728L);
    f32_to_bf16_k<<<512,  256, 0, stream>>>(W_O, Wob, 1048576L);

    // 1) QKV projection -> bf16 [8192][3072]  (256^2 pipelined gemm)
    gemm_bf16_256<bf16><<<dim3(12, 32), 512, 0, stream>>>(xb, qkvwb, QKVb, NROW, 3072, DM);

    // 2) RoPE + justnorm + scaling -> Qb/Kb/Vt
    rope_norm_qk<<<(H_ * NROW) / 4, 256, 0, stream>>>(QKVb, sqk, Qb, Kb, Vt);

    // 3) MFMA flash attention -> attno bf16 (overwrites qkvwb region)
    attn_mfma<<<1024, 256, 0, stream>>>(Qb, Kb, Vt, attno);

    // 4) W_O projection -> tbuf fp32 (QKVb region dead)
    gemm_bf16<float><<<dim3(8, 64), 256, 0, stream>>>(attno, Wob, tbuf, NROW, DM, DM);

    // 5) attention residual lerp-norm -> x1 fp32 + x1b bf16
    lerp_norm<<<NROW, 256, 0, stream>>>(x, tbuf, attn_alpha, 1.6f, x1, x1b);

    // 6) weight converts for MLP (Qb/Kb/Vt dead)
    f32_to_bf16_k<<<4096, 256, 0, stream>>>(Wu, Wub, 8388608L);
    f32_to_bf16_k<<<2048, 256, 0, stream>>>(Wv, Wvb, 4194304L);

    // 7) MLP in two M-halves: uv(half) = x1b @ Wu^T -> bf16; act -> res
    for (int half = 0; half < 2; half++) {
        gemm_bf16_256<bf16><<<dim3(32, 16), 512, 0, stream>>>(
            x1b + (long)half * 4096 * DM, Wub, uv, 4096, 8 * DM, DM);
        mlp_act<<<4096, 256, 0, stream>>>(uv, suv, res + (long)half * 4096 * 4096);
    }
    // note: mlp_act(half2) clobbers Wub region — Wub dead by then.

    // 8) t2 = res @ Wv^T -> fp32 (uv dead)
    gemm_bf16<float><<<dim3(8, 64), 256, 0, stream>>>(res, Wvb, t2, NROW, DM, 4 * DM);

    // 9) MLP residual lerp-norm -> out
    lerp_norm<<<NROW, 256, 0, stream>>>(x1, t2, mlp_alpha, 0.05f, out, (bf16*)nullptr);
}